// Round 15
// baseline (711.438 us; speedup 1.0000x reference)
//
#include <hip/hip_runtime.h>

typedef unsigned short u16;
typedef short s16x8 __attribute__((ext_vector_type(8)));
typedef float f32x4 __attribute__((ext_vector_type(4)));

#define S_TXTC 512
#define S_TOTC 2560
#define DM 3072
#define NH 24
#define HDM 128

__device__ __forceinline__ float b2f(u16 u){ unsigned int i = ((unsigned int)u)<<16; float f; __builtin_memcpy(&f,&i,4); return f; }
__device__ __forceinline__ u16 f2b(float f){ unsigned int i; __builtin_memcpy(&i,&f,4); unsigned int r = i + 0x7FFFu + ((i>>16)&1u); return (u16)(r>>16); }
__device__ __forceinline__ unsigned int pk2(float lo, float hi){
  return (unsigned int)f2b(lo) | ((unsigned int)f2b(hi)<<16);
}
__device__ __forceinline__ s16x8 pk8(float4 a, float4 b){
  s16x8 r;
  r[0]=(short)f2b(a.x); r[1]=(short)f2b(a.y); r[2]=(short)f2b(a.z); r[3]=(short)f2b(a.w);
  r[4]=(short)f2b(b.x); r[5]=(short)f2b(b.y); r[6]=(short)f2b(b.z); r[7]=(short)f2b(b.w);
  return r;
}
__device__ __forceinline__ void g2l16(const void* g, void* l){
  __builtin_amdgcn_global_load_lds((const __attribute__((address_space(1))) void*)g,
                                   (__attribute__((address_space(3))) void*)l, 16, 0, 0);
}

__global__ __launch_bounds__(256) void fillv(float* __restrict__ p, int n, float v){
  int i = blockIdx.x*256 + threadIdx.x;
  if (i < n) p[i] = v;
}

// ---------------- cast hidden+enc fp32 -> bf16 + concat biases (merged) ----------------
__global__ __launch_bounds__(256) void castbias(const float* __restrict__ a, const float* __restrict__ b,
    u16* __restrict__ dst, int na8, int n8,
    const float* __restrict__ b0, const float* __restrict__ b1, const float* __restrict__ b2,
    const float* __restrict__ c0, const float* __restrict__ c1, const float* __restrict__ c2,
    float* __restrict__ bdst){
  int blk = blockIdx.x;
  if (blk < 3840){
    int i = blk*256 + threadIdx.x;
    if (i >= n8) return;
    const float* src = (i < na8)? a + (size_t)i*8 : b + (size_t)(i-na8)*8;
    float4 f0 = *(const float4*)src;
    float4 f1 = *(const float4*)(src+4);
    *(s16x8*)(dst + (size_t)i*8) = pk8(f0,f1);
  } else {
    int i = (blk-3840)*256 + threadIdx.x;
    if (i >= 18432) return;
    int j = (i < 9216)? i : i - 9216;
    const float* s0 = (i<9216)? b0 : c0; const float* s1 = (i<9216)? b1 : c1; const float* s2 = (i<9216)? b2 : c2;
    bdst[i] = (j<3072)? s0[j] : (j<6144? s1[j-3072] : s2[j-6144]);
  }
}

__global__ __launch_bounds__(256) void ktrans3(const float* __restrict__ W0, const float* __restrict__ W1,
    const float* __restrict__ W2, u16* __restrict__ D0, u16* __restrict__ D1, u16* __restrict__ D2){
  const float* W = (blockIdx.z==0)? W0 : ((blockIdx.z==1)? W1 : W2);
  u16* Wt = (blockIdx.z==0)? D0 : ((blockIdx.z==1)? D1 : D2);
  __shared__ __align__(16) u16 t[64*72];
  int nt = blockIdx.x*64, kt_ = blockIdx.y*64;
  int tid = threadIdx.x;
  #pragma unroll
  for (int i=0;i<2;i++){
    int q = tid + 256*i;
    int r = q>>3, c8 = (q&7)*8;
    float4 f0 = *(const float4*)(W + (size_t)(kt_+r)*DM + nt + c8);
    float4 f1 = *(const float4*)(W + (size_t)(kt_+r)*DM + nt + c8 + 4);
    *(s16x8*)&t[r*72 + c8] = pk8(f0,f1);
  }
  __syncthreads();
  #pragma unroll
  for (int i=0;i<2;i++){
    int q = tid + 256*i;
    int n = q>>3, k8 = (q&7)*8;
    s16x8 v;
    #pragma unroll
    for (int j=0;j<8;j++) v[j] = (short)t[(k8+j)*72 + n];
    *(s16x8*)(Wt + (size_t)(nt+n)*DM + kt_ + k8) = v;
  }
}

// ---------------- m97-style bf16 GEMM core ----------------
template<int OUT32>
__device__ __forceinline__ void gcore(u16* la, u16* lb,
    const u16* __restrict__ A, const u16* __restrict__ Bt,
    const float* __restrict__ bias, void* __restrict__ Cv,
    int ldc, int rb, int crb, int cb){
  const int K = DM;
  int tid = threadIdx.x, w = tid>>6, l = tid&63, g = l>>4, c16 = l&15;
  int wr = (w>>1)*64, wc = (w&1)*64;
  f32x4 acc[4][4] = {};
  const u16* aL = A  + (size_t)(rb + w*32 + (l>>2))*K + (l&3)*8;
  const u16* bL = Bt + (size_t)(cb + w*32 + (l>>2))*K + (l&3)*8;
  u16* laB = la + w*1024;
  u16* lbB = lb + w*1024;
  for (int ks=0; ks<K; ks+=32){
    g2l16(aL + ks,                laB);
    g2l16(aL + 16*(size_t)K + ks, laB + 512);
    g2l16(bL + ks,                lbB);
    g2l16(bL + 16*(size_t)K + ks, lbB + 512);
    __syncthreads();
    s16x8 af[4], bf[4];
    #pragma unroll
    for (int m=0;m<4;m++) af[m] = *(const s16x8*)&la[(wr + m*16 + c16)*32 + g*8];
    #pragma unroll
    for (int n=0;n<4;n++) bf[n] = *(const s16x8*)&lb[(wc + n*16 + c16)*32 + g*8];
    #pragma unroll
    for (int m=0;m<4;m++)
      #pragma unroll
      for (int n=0;n<4;n++)
        acc[m][n] = __builtin_amdgcn_mfma_f32_16x16x32_bf16(af[m], bf[n], acc[m][n], 0,0,0);
    __syncthreads();
  }
  #pragma unroll
  for (int n=0;n<4;n++){
    int col = cb + wc + n*16 + c16;
    float bv = bias[col];
    #pragma unroll
    for (int m=0;m<4;m++){
      int r0 = crb + wr + m*16 + g*4;
      #pragma unroll
      for (int r=0;r<4;r++){
        float oo = acc[m][n][r] + bv;
        if (OUT32) ((float*)Cv)[(size_t)(r0+r)*ldc + col] = oo;
        else       ((u16*)Cv)[(size_t)(r0+r)*ldc + col] = f2b(oo);
      }
    }
  }
}

// XCD-chunked bijective block swizzle (requires nwg % 8 == 0)
__device__ __forceinline__ void xcd_swz(int& bx, int& by){
  int gx = gridDim.x, nwg = gx*gridDim.y;
  int id = blockIdx.y*gx + blockIdx.x;
  int q = nwg>>3;
  int nid = (id&7)*q + (id>>3);
  bx = nid % gx; by = nid / gx;
}

__global__ __launch_bounds__(256) void qkv_gemm(const u16* __restrict__ A, const u16* __restrict__ Bt,
                                                const float* __restrict__ bias, u16* __restrict__ C){
  __shared__ __align__(16) u16 la[4096];
  __shared__ __align__(16) u16 lb[4096];
  int bx, by; xcd_swz(bx, by);
  gcore<0>(la, lb, A, Bt, bias, C, 3*DM, bx*128, bx*128, by*128);
}

__global__ __launch_bounds__(256) void out_gemm(const u16* __restrict__ hsb,
    const u16* __restrict__ woT, const u16* __restrict__ woaT,
    const float* __restrict__ bo, const float* __restrict__ boa, float* __restrict__ out){
  __shared__ __align__(16) u16 la[4096];
  __shared__ __align__(16) u16 lb[4096];
  int bx, by; xcd_swz(bx, by);
  bool txt = (bx < 4);
  int rb = bx*128;
  const u16* Bt = txt? woaT : woT;
  const float* bias = txt? boa : bo;
  float* dst = txt? out + (size_t)2048*DM : out;
  int crb = txt? rb : rb - 512;
  gcore<1>(la, lb, hsb, Bt, bias, dst, DM, rb, crb, by*128);
}

// ---------------- fused epilogues + adapter projections ----------------
__global__ __launch_bounds__(256) void epi_fused(
    const u16* __restrict__ qkvI, const u16* __restrict__ qkvT,
    const float* __restrict__ nqw, const float* __restrict__ nkw,
    const float* __restrict__ naq, const float* __restrict__ nak,
    const float* __restrict__ fcos, const float* __restrict__ fsin,
    u16* __restrict__ qh, u16* __restrict__ kh, u16* __restrict__ vt,
    const float* __restrict__ ad, const float* __restrict__ Wkad, const float* __restrict__ Wvad,
    u16* __restrict__ vdk, u16* __restrict__ vdv){
  __shared__ __align__(16) u16 t[64*136];
  int blk = blockIdx.x;
  if (blk < 30720){
    int wid = blk*4 + (threadIdx.x>>6);
    int lane = threadIdx.x&63;
    int which = wid / (NH*S_TOTC);
    int rem = wid % (NH*S_TOTC);
    int h = rem / S_TOTC, tok = rem % S_TOTC;
    const u16* src = ((tok<S_TXTC)? qkvT + (size_t)tok*(3*DM) : qkvI + (size_t)(tok-S_TXTC)*(3*DM))
                     + which*DM + h*HDM;
    const float* nw = which? ((tok<S_TXTC)? nak : nkw) : ((tok<S_TXTC)? naq : nqw);
    int d = lane*2;
    unsigned int u = *(const unsigned int*)(src + d);
    float x0 = b2f((u16)(u&0xffffu)), x1 = b2f((u16)(u>>16));
    float ss = x0*x0 + x1*x1;
    #pragma unroll
    for (int m=1;m<64;m<<=1) ss += __shfl_xor(ss, m);
    float rr = rsqrtf(ss*(1.f/128.f) + 1e-6f);
    float y0 = x0*rr*nw[d];
    float y1 = x1*rr*nw[d+1];
    float2 cc = *(const float2*)(fcos + (size_t)tok*HDM + d);
    float2 sn = *(const float2*)(fsin + (size_t)tok*HDM + d);
    // Q: fold 1/sqrt(HD) * log2(e) so attn softmax runs in exp2 domain
    float sc = which? 1.0f : 0.1275174436f;
    float o0 = (y0*cc.x - y1*sn.x)*sc;
    float o1 = (y1*cc.y + y0*sn.y)*sc;
    u16* dst = (which? kh : qh) + ((size_t)h*S_TOTC + tok)*HDM + d;
    *(unsigned int*)dst = pk2(o0, o1);
  } else if (blk < 31680){
    int bv = blk - 30720;
    int h = bv % NH, tb = bv / NH;
    int tok0 = tb*64, tid = threadIdx.x;
    #pragma unroll
    for (int i=0;i<4;i++){
      int q = tid + 256*i;
      int tr = q>>4, c8 = (q&15)*8;
      int tok = tok0 + tr;
      const u16* src = ((tok<S_TXTC)? qkvT + (size_t)tok*(3*DM) : qkvI + (size_t)(tok-S_TXTC)*(3*DM))
                       + 2*DM + h*HDM;
      *(s16x8*)&t[tr*136 + c8] = *(const s16x8*)(src + c8);
    }
    __syncthreads();
    #pragma unroll
    for (int i=0;i<4;i++){
      int q = tid + 256*i;
      int d = q>>3, j8 = (q&7)*8;
      s16x8 v;
      #pragma unroll
      for (int j=0;j<8;j++) v[j] = (short)t[(j8+j)*136 + d];
      *(s16x8*)(vt + ((size_t)h*HDM + d)*S_TOTC + tok0 + j8) = v;
    }
  } else {
    int wid = (blk-31680)*4 + (threadIdx.x>>6);
    int lane = threadIdx.x&63;
    int tensor = wid / (4*DM);
    int rem = wid % (4*DM);
    int tok = rem / DM, col = rem % DM;
    const float* Wp = tensor? Wvad : Wkad;
    float s = 0.f;
    #pragma unroll
    for (int i=0;i<16;i++){
      int k = lane + 64*i;
      s += ad[tok*1024 + k] * Wp[(size_t)k*DM + col];
    }
    #pragma unroll
    for (int m=1;m<64;m<<=1) s += __shfl_xor(s, m);
    if (lane==0){
      int hh = col>>7, d = col&127;
      (tensor? vdv : vdk)[(hh*4+tok)*HDM + d] = f2b(s);
    }
  }
}

// ---------------- attn: QBLK=128, 8 waves, KVBLK=64, g2l16 dbuf, exp2 softmax ----------------
__global__ __launch_bounds__(512,2) void attnk(const u16* __restrict__ qh, const u16* __restrict__ kh,
    const u16* __restrict__ vt, const u16* __restrict__ vdk, const u16* __restrict__ vdv,
    const float* __restrict__ bscale, u16* __restrict__ hs){
  __shared__ __align__(16) u16 kts[2][64*128];   // [key][d], slot ^= row&7 (via pre-swizzled source)
  __shared__ __align__(16) u16 vts[2][128*64];   // [d][key], slot ^= row&7
  __shared__ __align__(16) u16 pwb[128*64];      // [q][key], slot ^= row&7 (wave-private rows)
  int h = blockIdx.y, qb = blockIdx.x*128;
  int tid = threadIdx.x, w = tid>>6, l = tid&63, g = l>>4, c16 = l&15;
  int qrow = qb + w*16 + c16;
  int c7 = c16&7;
  s16x8 qf[4];
  #pragma unroll
  for (int kc=0;kc<4;kc++) qf[kc] = *(const s16x8*)(qh + ((size_t)h*S_TOTC + qrow)*HDM + kc*32 + g*8);
  f32x4 acc[8];
  #pragma unroll
  for (int dt=0;dt<8;dt++) acc[dt] = f32x4{0.f,0.f,0.f,0.f};
  float m_[4] = {-3e38f,-3e38f,-3e38f,-3e38f};
  float l_[4] = {0.f,0.f,0.f,0.f};
  const u16* khB = kh + (size_t)h*S_TOTC*HDM;
  const u16* vtB = vt + (size_t)h*HDM*S_TOTC;

  auto STAGE = [&](int buf, int kb){
    #pragma unroll
    for (int c=0;c<2;c++){
      int krow = w*8 + c*4 + (l>>4);
      int kchunk = (l&15) ^ (krow&7);
      g2l16(khB + (size_t)(kb + krow)*HDM + kchunk*8, &kts[buf][w*1024 + c*512]);
      int vrow = w*16 + c*8 + (l>>3);
      int vchunk = (l&7) ^ (vrow&7);
      g2l16(vtB + (size_t)vrow*S_TOTC + kb + vchunk*8, &vts[buf][w*1024 + c*512]);
    }
  };
  auto COMPUTE = [&](int buf){
    f32x4 s[4];
    #pragma unroll
    for (int su=0;su<4;su++) s[su] = f32x4{0.f,0.f,0.f,0.f};
    __builtin_amdgcn_s_setprio(1);
    #pragma unroll
    for (int su=0;su<4;su++)
      #pragma unroll
      for (int kc=0;kc<4;kc++){
        s16x8 kf = *(const s16x8*)&kts[buf][(su*16+c16)*128 + ((kc*4+g) ^ c7)*8];
        s[su] = __builtin_amdgcn_mfma_f32_16x16x32_bf16(qf[kc], kf, s[su], 0,0,0);
      }
    __builtin_amdgcn_s_setprio(0);
    float tm[4];
    #pragma unroll
    for (int r=0;r<4;r++)
      tm[r] = fmaxf(fmaxf(s[0][r],s[1][r]), fmaxf(s[2][r],s[3][r]));
    #pragma unroll
    for (int m=1;m<16;m<<=1)
      #pragma unroll
      for (int r=0;r<4;r++) tm[r] = fmaxf(tm[r], __shfl_xor(tm[r], m));
    bool need = !__all(tm[0]<=m_[0]+11.5415603f && tm[1]<=m_[1]+11.5415603f &&
                       tm[2]<=m_[2]+11.5415603f && tm[3]<=m_[3]+11.5415603f);
    if (need){
      float corr[4];
      #pragma unroll
      for (int r=0;r<4;r++){
        float mn = fmaxf(m_[r], tm[r]);
        corr[r] = exp2f(m_[r]-mn);
        m_[r] = mn;
        l_[r] *= corr[r];
      }
      #pragma unroll
      for (int dt=0;dt<8;dt++)
        #pragma unroll
        for (int r=0;r<4;r++) acc[dt][r] *= corr[r];
    }
    float rs[4];
    #pragma unroll
    for (int r=0;r<4;r++){
      rs[r] = 0.f;
      #pragma unroll
      for (int su=0;su<4;su++){ s[su][r] = exp2f(s[su][r]-m_[r]); rs[r] += s[su][r]; }
    }
    #pragma unroll
    for (int m=1;m<16;m<<=1)
      #pragma unroll
      for (int r=0;r<4;r++) rs[r] += __shfl_xor(rs[r], m);
    #pragma unroll
    for (int r=0;r<4;r++) l_[r] += rs[r];
    #pragma unroll
    for (int su=0;su<4;su++){
      int kslot = su*2 + (c16>>3);
      #pragma unroll
      for (int r=0;r<4;r++){
        int prow = w*16 + g*4 + r;
        pwb[prow*64 + (kslot ^ (prow&7))*8 + c7] = f2b(s[su][r]);
      }
    }
    int prow = w*16 + c16;
    s16x8 pf0 = *(const s16x8*)&pwb[prow*64 + ((0+g) ^ c7)*8];
    s16x8 pf1 = *(const s16x8*)&pwb[prow*64 + ((4+g) ^ c7)*8];
    __builtin_amdgcn_s_setprio(1);
    #pragma unroll
    for (int dt=0;dt<8;dt++){
      int vrow = dt*16 + c16;
      s16x8 vf0 = *(const s16x8*)&vts[buf][vrow*64 + ((0+g) ^ c7)*8];
      acc[dt] = __builtin_amdgcn_mfma_f32_16x16x32_bf16(pf0, vf0, acc[dt], 0,0,0);
      s16x8 vf1 = *(const s16x8*)&vts[buf][vrow*64 + ((4+g) ^ c7)*8];
      acc[dt] = __builtin_amdgcn_mfma_f32_16x16x32_bf16(pf1, vf1, acc[dt], 0,0,0);
    }
    __builtin_amdgcn_s_setprio(0);
  };

  STAGE(0, 0);
  __syncthreads();
  int cur = 0;
  for (int kb=0; kb<S_TOTC; kb+=64){
    if (kb+64 < S_TOTC) STAGE(cur^1, kb+64);
    COMPUTE(cur);
    __syncthreads();
    cur ^= 1;
  }

  // adapter cross-attention tile (4 valid keys), exp2 domain, stale rows masked by P=0
  if (tid < 64){
    int row = tid>>4, slot = (tid&15) ^ (row&7);
    *(s16x8*)&kts[0][row*128 + slot*8] = *(const s16x8*)(vdk + (h*4+(tid>>4))*HDM + (tid&15)*8);
  } else if (tid < 192){
    int d = tid - 64;
    int sl0 = (d&7)*8;
    #pragma unroll
    for (int key=0;key<4;key++) vts[0][d*64 + sl0 + key] = vdv[(h*4+key)*HDM + d];
  }
  __syncthreads();
  f32x4 s2 = {0.f,0.f,0.f,0.f};
  #pragma unroll
  for (int kc=0;kc<4;kc++){
    s16x8 kf = *(const s16x8*)&kts[0][c16*128 + ((kc*4+g) ^ c7)*8];
    s2 = __builtin_amdgcn_mfma_f32_16x16x32_bf16(qf[kc], kf, s2, 0,0,0);
  }
  bool valid = (c16 < 4);
  float m2[4], l2[4];
  #pragma unroll
  for (int r=0;r<4;r++) m2[r] = valid? s2[r] : -3e38f;
  #pragma unroll
  for (int m=1;m<16;m<<=1)
    #pragma unroll
    for (int r=0;r<4;r++) m2[r] = fmaxf(m2[r], __shfl_xor(m2[r], m));
  #pragma unroll
  for (int r=0;r<4;r++){ float p = valid? exp2f(s2[r]-m2[r]) : 0.f; s2[r]=p; l2[r]=p; }
  #pragma unroll
  for (int m=1;m<16;m<<=1)
    #pragma unroll
    for (int r=0;r<4;r++) l2[r] += __shfl_xor(l2[r], m);
  #pragma unroll
  for (int r=0;r<4;r++){
    int prow = w*16 + g*4 + r;
    int s0 = (c16>>3) ^ (prow&7);
    int s1 = (2 + (c16>>3)) ^ (prow&7);
    pwb[prow*64 + s0*8 + c7] = f2b(s2[r]);
    pwb[prow*64 + s1*8 + c7] = (u16)0;
  }
  int prow2 = w*16 + c16;
  s16x8 pf2 = *(const s16x8*)&pwb[prow2*64 + (g ^ c7)*8];
  f32x4 a2[8];
  #pragma unroll
  for (int dt=0;dt<8;dt++) a2[dt] = f32x4{0.f,0.f,0.f,0.f};
  #pragma unroll
  for (int dt=0;dt<8;dt++){
    int vrow = dt*16 + c16;
    s16x8 vf = *(const s16x8*)&vts[0][vrow*64 + (g ^ c7)*8];
    a2[dt] = __builtin_amdgcn_mfma_f32_16x16x32_bf16(pf2, vf, a2[dt], 0,0,0);
  }
  float sb = bscale[0];
  float rl[4], rl2[4];
  #pragma unroll
  for (int r=0;r<4;r++){ rl[r] = 1.f/l_[r]; rl2[r] = sb/l2[r]; }
  #pragma unroll
  for (int dt=0;dt<8;dt++)
    #pragma unroll
    for (int r=0;r<4;r++){
      int tok = qb + w*16 + g*4 + r;
      int col = h*HDM + dt*16 + c16;
      hs[(size_t)tok*DM + col] = f2b(acc[dt][r]*rl[r] + a2[dt][r]*rl2[r]);
    }
}

extern "C" void kernel_launch(void* const* d_in, const int* in_sizes, int n_in,
                              void* d_out, int out_size, void* d_ws, size_t ws_size,
                              hipStream_t stream){
  static const int expect[28] = {
    6291456, 1572864, 4096, 327680, 327680,
    9437184, 3072, 9437184, 3072, 9437184, 3072, 128, 128,
    9437184, 3072, 9437184, 3072, 9437184, 3072, 128, 128,
    9437184, 3072, 9437184, 3072, 3145728, 3145728, 1 };
  bool ok = (n_in == 28);
  if (ok) for (int i=0;i<28;i++) if (in_sizes[i] != expect[i]) { ok = false; break; }
  if (!ok){ fillv<<<(out_size+255)/256,256,0,stream>>>((float*)d_out, out_size, 7.0f); return; }
  if (ws_size < 119611392ull){ fillv<<<(out_size+255)/256,256,0,stream>>>((float*)d_out, out_size, 9.0f); return; }

  const float* hidden = (const float*)d_in[0];
  const float* enc    = (const float*)d_in[1];
  const float* adapt  = (const float*)d_in[2];
  const float* fcos   = (const float*)d_in[3];
  const float* fsin   = (const float*)d_in[4];
  const float* Wq  = (const float*)d_in[5];  const float* bq  = (const float*)d_in[6];
  const float* Wk  = (const float*)d_in[7];  const float* bk  = (const float*)d_in[8];
  const float* Wv  = (const float*)d_in[9];  const float* bv  = (const float*)d_in[10];
  const float* nqw = (const float*)d_in[11]; const float* nkw = (const float*)d_in[12];
  const float* Wqa = (const float*)d_in[13]; const float* bqa = (const float*)d_in[14];
  const float* Wka = (const float*)d_in[15]; const float* bka = (const float*)d_in[16];
  const float* Wva = (const float*)d_in[17]; const float* bva = (const float*)d_in[18];
  const float* naq = (const float*)d_in[19]; const float* nak = (const float*)d_in[20];
  const float* Wo  = (const float*)d_in[21]; const float* bo  = (const float*)d_in[22];
  const float* Woa = (const float*)d_in[23]; const float* boa = (const float*)d_in[24];
  const float* Wkad = (const float*)d_in[25]; const float* Wvad = (const float*)d_in[26];
  const float* bsc  = (const float*)d_in[27];
  float* out = (float*)d_out;

  char* ws = (char*)d_ws;
  u16* wt3   = (u16*)(ws);
  u16* kh    = (u16*)(ws);
  u16* vth   = (u16*)(ws + 15728640);
  u16* vdk   = (u16*)(ws + 31457280);
  u16* vdv   = (u16*)(ws + 31481856);
  u16* woaT  = (u16*)(ws + 33554432);
  u16* hbf   = (u16*)(ws + 56623104);
  u16* qh    = (u16*)(ws + 56623104);
  u16* qkvI  = (u16*)(ws + 72351744);
  u16* hsb   = (u16*)(ws + 72351744);
  u16* woT   = (u16*)(ws + 88080384);
  u16* qkvT  = (u16*)(ws + 110100480);
  float* biasA = (float*)(ws + 119537664);
  float* biasB = (float*)(ws + 119574528);

  castbias<<<3912,256,0,stream>>>(hidden, enc, hbf, 786432, 983040,
                                  bq,bk,bv, bqa,bka,bva, biasA);
  ktrans3<<<dim3(48,48,3),256,0,stream>>>(Wq, Wk, Wv, wt3, wt3 + (size_t)DM*DM, wt3 + (size_t)2*DM*DM);
  qkv_gemm<<<dim3(16,72),256,0,stream>>>(hbf, wt3, biasA, qkvI);
  ktrans3<<<dim3(48,48,3),256,0,stream>>>(Wqa, Wka, Wva, wt3, wt3 + (size_t)DM*DM, wt3 + (size_t)2*DM*DM);
  qkv_gemm<<<dim3(4,72),256,0,stream>>>(hbf + (size_t)2048*DM, wt3, biasB, qkvT);
  epi_fused<<<37824,256,0,stream>>>(qkvI, qkvT, nqw,nkw,naq,nak, fcos,fsin, qh, kh, vth,
                                    adapt, Wkad, Wvad, vdk, vdv);
  attnk<<<dim3(20,24),512,0,stream>>>(qh, kh, vth, vdk, vdv, bsc, hsb);
  ktrans3<<<dim3(48,48,2),256,0,stream>>>(Wo, Woa, Woa, woT, woaT, woaT);
  out_gemm<<<dim3(20,24),256,0,stream>>>(hsb, woT, woaT, bo, boa, out);
}

// Round 16
// 700.707 us; speedup vs baseline: 1.0153x; 1.0153x over previous
//
#include <hip/hip_runtime.h>

typedef unsigned short u16;
typedef short s16x8 __attribute__((ext_vector_type(8)));
typedef float f32x4 __attribute__((ext_vector_type(4)));

#define S_TXTC 512
#define S_TOTC 2560
#define DM 3072
#define NH 24
#define HDM 128

__device__ __forceinline__ float b2f(u16 u){ unsigned int i = ((unsigned int)u)<<16; float f; __builtin_memcpy(&f,&i,4); return f; }
__device__ __forceinline__ u16 f2b(float f){ unsigned int i; __builtin_memcpy(&i,&f,4); unsigned int r = i + 0x7FFFu + ((i>>16)&1u); return (u16)(r>>16); }
__device__ __forceinline__ unsigned int pk2(float lo, float hi){
  return (unsigned int)f2b(lo) | ((unsigned int)f2b(hi)<<16);
}
__device__ __forceinline__ s16x8 pk8(float4 a, float4 b){
  s16x8 r;
  r[0]=(short)f2b(a.x); r[1]=(short)f2b(a.y); r[2]=(short)f2b(a.z); r[3]=(short)f2b(a.w);
  r[4]=(short)f2b(b.x); r[5]=(short)f2b(b.y); r[6]=(short)f2b(b.z); r[7]=(short)f2b(b.w);
  return r;
}
__device__ __forceinline__ void g2l16(const void* g, void* l){
  __builtin_amdgcn_global_load_lds((const __attribute__((address_space(1))) void*)g,
                                   (__attribute__((address_space(3))) void*)l, 16, 0, 0);
}
__device__ __forceinline__ float fexp2(float x){ return __builtin_amdgcn_exp2f(x); }  // native v_exp_f32 (2^x)

__global__ __launch_bounds__(256) void fillv(float* __restrict__ p, int n, float v){
  int i = blockIdx.x*256 + threadIdx.x;
  if (i < n) p[i] = v;
}

// ---------------- cast hidden+enc fp32 -> bf16 + concat biases (merged) ----------------
__global__ __launch_bounds__(256) void castbias(const float* __restrict__ a, const float* __restrict__ b,
    u16* __restrict__ dst, int na8, int n8,
    const float* __restrict__ b0, const float* __restrict__ b1, const float* __restrict__ b2,
    const float* __restrict__ c0, const float* __restrict__ c1, const float* __restrict__ c2,
    float* __restrict__ bdst){
  int blk = blockIdx.x;
  if (blk < 3840){
    int i = blk*256 + threadIdx.x;
    if (i >= n8) return;
    const float* src = (i < na8)? a + (size_t)i*8 : b + (size_t)(i-na8)*8;
    float4 f0 = *(const float4*)src;
    float4 f1 = *(const float4*)(src+4);
    *(s16x8*)(dst + (size_t)i*8) = pk8(f0,f1);
  } else {
    int i = (blk-3840)*256 + threadIdx.x;
    if (i >= 18432) return;
    int j = (i < 9216)? i : i - 9216;
    const float* s0 = (i<9216)? b0 : c0; const float* s1 = (i<9216)? b1 : c1; const float* s2 = (i<9216)? b2 : c2;
    bdst[i] = (j<3072)? s0[j] : (j<6144? s1[j-3072] : s2[j-6144]);
  }
}

__global__ __launch_bounds__(256) void ktrans3(const float* __restrict__ W0, const float* __restrict__ W1,
    const float* __restrict__ W2, u16* __restrict__ D0, u16* __restrict__ D1, u16* __restrict__ D2){
  const float* W = (blockIdx.z==0)? W0 : ((blockIdx.z==1)? W1 : W2);
  u16* Wt = (blockIdx.z==0)? D0 : ((blockIdx.z==1)? D1 : D2);
  __shared__ __align__(16) u16 t[64*72];
  int nt = blockIdx.x*64, kt_ = blockIdx.y*64;
  int tid = threadIdx.x;
  #pragma unroll
  for (int i=0;i<2;i++){
    int q = tid + 256*i;
    int r = q>>3, c8 = (q&7)*8;
    float4 f0 = *(const float4*)(W + (size_t)(kt_+r)*DM + nt + c8);
    float4 f1 = *(const float4*)(W + (size_t)(kt_+r)*DM + nt + c8 + 4);
    *(s16x8*)&t[r*72 + c8] = pk8(f0,f1);
  }
  __syncthreads();
  #pragma unroll
  for (int i=0;i<2;i++){
    int q = tid + 256*i;
    int n = q>>3, k8 = (q&7)*8;
    s16x8 v;
    #pragma unroll
    for (int j=0;j<8;j++) v[j] = (short)t[(k8+j)*72 + n];
    *(s16x8*)(Wt + (size_t)(nt+n)*DM + kt_ + k8) = v;
  }
}

// ---------------- m97-style bf16 GEMM core ----------------
template<int OUT32>
__device__ __forceinline__ void gcore(u16* la, u16* lb,
    const u16* __restrict__ A, const u16* __restrict__ Bt,
    const float* __restrict__ bias, void* __restrict__ Cv,
    int ldc, int rb, int crb, int cb){
  const int K = DM;
  int tid = threadIdx.x, w = tid>>6, l = tid&63, g = l>>4, c16 = l&15;
  int wr = (w>>1)*64, wc = (w&1)*64;
  f32x4 acc[4][4] = {};
  const u16* aL = A  + (size_t)(rb + w*32 + (l>>2))*K + (l&3)*8;
  const u16* bL = Bt + (size_t)(cb + w*32 + (l>>2))*K + (l&3)*8;
  u16* laB = la + w*1024;
  u16* lbB = lb + w*1024;
  for (int ks=0; ks<K; ks+=32){
    g2l16(aL + ks,                laB);
    g2l16(aL + 16*(size_t)K + ks, laB + 512);
    g2l16(bL + ks,                lbB);
    g2l16(bL + 16*(size_t)K + ks, lbB + 512);
    __syncthreads();
    s16x8 af[4], bf[4];
    #pragma unroll
    for (int m=0;m<4;m++) af[m] = *(const s16x8*)&la[(wr + m*16 + c16)*32 + g*8];
    #pragma unroll
    for (int n=0;n<4;n++) bf[n] = *(const s16x8*)&lb[(wc + n*16 + c16)*32 + g*8];
    #pragma unroll
    for (int m=0;m<4;m++)
      #pragma unroll
      for (int n=0;n<4;n++)
        acc[m][n] = __builtin_amdgcn_mfma_f32_16x16x32_bf16(af[m], bf[n], acc[m][n], 0,0,0);
    __syncthreads();
  }
  #pragma unroll
  for (int n=0;n<4;n++){
    int col = cb + wc + n*16 + c16;
    float bv = bias[col];
    #pragma unroll
    for (int m=0;m<4;m++){
      int r0 = crb + wr + m*16 + g*4;
      #pragma unroll
      for (int r=0;r<4;r++){
        float oo = acc[m][n][r] + bv;
        if (OUT32) ((float*)Cv)[(size_t)(r0+r)*ldc + col] = oo;
        else       ((u16*)Cv)[(size_t)(r0+r)*ldc + col] = f2b(oo);
      }
    }
  }
}

// XCD-chunked bijective block swizzle (requires nwg % 8 == 0)
__device__ __forceinline__ void xcd_swz(int& bx, int& by){
  int gx = gridDim.x, nwg = gx*gridDim.y;
  int id = blockIdx.y*gx + blockIdx.x;
  int q = nwg>>3;
  int nid = (id&7)*q + (id>>3);
  bx = nid % gx; by = nid / gx;
}

__global__ __launch_bounds__(256) void qkv_gemm(const u16* __restrict__ A, const u16* __restrict__ Bt,
                                                const float* __restrict__ bias, u16* __restrict__ C){
  __shared__ __align__(16) u16 la[4096];
  __shared__ __align__(16) u16 lb[4096];
  int bx, by; xcd_swz(bx, by);
  gcore<0>(la, lb, A, Bt, bias, C, 3*DM, bx*128, bx*128, by*128);
}

__global__ __launch_bounds__(256) void out_gemm(const u16* __restrict__ hsb,
    const u16* __restrict__ woT, const u16* __restrict__ woaT,
    const float* __restrict__ bo, const float* __restrict__ boa, float* __restrict__ out){
  __shared__ __align__(16) u16 la[4096];
  __shared__ __align__(16) u16 lb[4096];
  int bx, by; xcd_swz(bx, by);
  bool txt = (bx < 4);
  int rb = bx*128;
  const u16* Bt = txt? woaT : woT;
  const float* bias = txt? boa : bo;
  float* dst = txt? out + (size_t)2048*DM : out;
  int crb = txt? rb : rb - 512;
  gcore<1>(la, lb, hsb, Bt, bias, dst, DM, rb, crb, by*128);
}

// ---------------- fused epilogues + adapter projections ----------------
__global__ __launch_bounds__(256) void epi_fused(
    const u16* __restrict__ qkvI, const u16* __restrict__ qkvT,
    const float* __restrict__ nqw, const float* __restrict__ nkw,
    const float* __restrict__ naq, const float* __restrict__ nak,
    const float* __restrict__ fcos, const float* __restrict__ fsin,
    u16* __restrict__ qh, u16* __restrict__ kh, u16* __restrict__ vt,
    const float* __restrict__ ad, const float* __restrict__ Wkad, const float* __restrict__ Wvad,
    u16* __restrict__ vdk, u16* __restrict__ vdv){
  __shared__ __align__(16) u16 t[64*136];
  int blk = blockIdx.x;
  if (blk < 30720){
    int wid = blk*4 + (threadIdx.x>>6);
    int lane = threadIdx.x&63;
    int which = wid / (NH*S_TOTC);
    int rem = wid % (NH*S_TOTC);
    int h = rem / S_TOTC, tok = rem % S_TOTC;
    const u16* src = ((tok<S_TXTC)? qkvT + (size_t)tok*(3*DM) : qkvI + (size_t)(tok-S_TXTC)*(3*DM))
                     + which*DM + h*HDM;
    const float* nw = which? ((tok<S_TXTC)? nak : nkw) : ((tok<S_TXTC)? naq : nqw);
    int d = lane*2;
    unsigned int u = *(const unsigned int*)(src + d);
    float x0 = b2f((u16)(u&0xffffu)), x1 = b2f((u16)(u>>16));
    float ss = x0*x0 + x1*x1;
    #pragma unroll
    for (int m=1;m<64;m<<=1) ss += __shfl_xor(ss, m);
    float rr = rsqrtf(ss*(1.f/128.f) + 1e-6f);
    float y0 = x0*rr*nw[d];
    float y1 = x1*rr*nw[d+1];
    float2 cc = *(const float2*)(fcos + (size_t)tok*HDM + d);
    float2 sn = *(const float2*)(fsin + (size_t)tok*HDM + d);
    // Q: fold 1/sqrt(HD) * log2(e) so attn softmax runs in exp2 domain
    float sc = which? 1.0f : 0.1275174436f;
    float o0 = (y0*cc.x - y1*sn.x)*sc;
    float o1 = (y1*cc.y + y0*sn.y)*sc;
    u16* dst = (which? kh : qh) + ((size_t)h*S_TOTC + tok)*HDM + d;
    *(unsigned int*)dst = pk2(o0, o1);
  } else if (blk < 31680){
    int bv = blk - 30720;
    int h = bv % NH, tb = bv / NH;
    int tok0 = tb*64, tid = threadIdx.x;
    #pragma unroll
    for (int i=0;i<4;i++){
      int q = tid + 256*i;
      int tr = q>>4, c8 = (q&15)*8;
      int tok = tok0 + tr;
      const u16* src = ((tok<S_TXTC)? qkvT + (size_t)tok*(3*DM) : qkvI + (size_t)(tok-S_TXTC)*(3*DM))
                       + 2*DM + h*HDM;
      *(s16x8*)&t[tr*136 + c8] = *(const s16x8*)(src + c8);
    }
    __syncthreads();
    #pragma unroll
    for (int i=0;i<4;i++){
      int q = tid + 256*i;
      int d = q>>3, j8 = (q&7)*8;
      s16x8 v;
      #pragma unroll
      for (int j=0;j<8;j++) v[j] = (short)t[(j8+j)*136 + d];
      *(s16x8*)(vt + ((size_t)h*HDM + d)*S_TOTC + tok0 + j8) = v;
    }
  } else {
    int wid = (blk-31680)*4 + (threadIdx.x>>6);
    int lane = threadIdx.x&63;
    int tensor = wid / (4*DM);
    int rem = wid % (4*DM);
    int tok = rem / DM, col = rem % DM;
    const float* Wp = tensor? Wvad : Wkad;
    float s = 0.f;
    #pragma unroll
    for (int i=0;i<16;i++){
      int k = lane + 64*i;
      s += ad[tok*1024 + k] * Wp[(size_t)k*DM + col];
    }
    #pragma unroll
    for (int m=1;m<64;m<<=1) s += __shfl_xor(s, m);
    if (lane==0){
      int hh = col>>7, d = col&127;
      (tensor? vdv : vdk)[(hh*4+tok)*HDM + d] = f2b(s);
    }
  }
}

// ---------------- attn: QBLK=128, 8 waves, KVBLK=64, g2l16 dbuf, native-exp2 softmax ----------------
__global__ __launch_bounds__(512,2) void attnk(const u16* __restrict__ qh, const u16* __restrict__ kh,
    const u16* __restrict__ vt, const u16* __restrict__ vdk, const u16* __restrict__ vdv,
    const float* __restrict__ bscale, u16* __restrict__ hs){
  __shared__ __align__(16) u16 kts[2][64*128];   // [key][d], slot ^= row&7 (via pre-swizzled source)
  __shared__ __align__(16) u16 vts[2][128*64];   // [d][key], slot ^= row&7
  __shared__ __align__(16) u16 pwb[128*64];      // [q][key], slot ^= row&7 (wave-private rows)
  int h = blockIdx.y, qb = blockIdx.x*128;
  int tid = threadIdx.x, w = tid>>6, l = tid&63, g = l>>4, c16 = l&15;
  int qrow = qb + w*16 + c16;
  int c7 = c16&7;
  s16x8 qf[4];
  #pragma unroll
  for (int kc=0;kc<4;kc++) qf[kc] = *(const s16x8*)(qh + ((size_t)h*S_TOTC + qrow)*HDM + kc*32 + g*8);
  f32x4 acc[8];
  #pragma unroll
  for (int dt=0;dt<8;dt++) acc[dt] = f32x4{0.f,0.f,0.f,0.f};
  float m_[4] = {-3e38f,-3e38f,-3e38f,-3e38f};
  float l_[4] = {0.f,0.f,0.f,0.f};
  const u16* khB = kh + (size_t)h*S_TOTC*HDM;
  const u16* vtB = vt + (size_t)h*HDM*S_TOTC;

  auto STAGE = [&](int buf, int kb){
    #pragma unroll
    for (int c=0;c<2;c++){
      int krow = w*8 + c*4 + (l>>4);
      int kchunk = (l&15) ^ (krow&7);
      g2l16(khB + (size_t)(kb + krow)*HDM + kchunk*8, &kts[buf][w*1024 + c*512]);
      int vrow = w*16 + c*8 + (l>>3);
      int vchunk = (l&7) ^ (vrow&7);
      g2l16(vtB + (size_t)vrow*S_TOTC + kb + vchunk*8, &vts[buf][w*1024 + c*512]);
    }
  };
  auto COMPUTE = [&](int buf){
    f32x4 s[4];
    #pragma unroll
    for (int su=0;su<4;su++) s[su] = f32x4{0.f,0.f,0.f,0.f};
    __builtin_amdgcn_s_setprio(1);
    #pragma unroll
    for (int su=0;su<4;su++)
      #pragma unroll
      for (int kc=0;kc<4;kc++){
        s16x8 kf = *(const s16x8*)&kts[buf][(su*16+c16)*128 + ((kc*4+g) ^ c7)*8];
        s[su] = __builtin_amdgcn_mfma_f32_16x16x32_bf16(qf[kc], kf, s[su], 0,0,0);
      }
    __builtin_amdgcn_s_setprio(0);
    float tm[4];
    #pragma unroll
    for (int r=0;r<4;r++)
      tm[r] = fmaxf(fmaxf(s[0][r],s[1][r]), fmaxf(s[2][r],s[3][r]));
    #pragma unroll
    for (int m=1;m<16;m<<=1)
      #pragma unroll
      for (int r=0;r<4;r++) tm[r] = fmaxf(tm[r], __shfl_xor(tm[r], m));
    bool need = !__all(tm[0]<=m_[0]+11.5415603f && tm[1]<=m_[1]+11.5415603f &&
                       tm[2]<=m_[2]+11.5415603f && tm[3]<=m_[3]+11.5415603f);
    if (need){
      float corr[4];
      #pragma unroll
      for (int r=0;r<4;r++){
        float mn = fmaxf(m_[r], tm[r]);
        corr[r] = fexp2(m_[r]-mn);
        m_[r] = mn;
        l_[r] *= corr[r];
      }
      #pragma unroll
      for (int dt=0;dt<8;dt++)
        #pragma unroll
        for (int r=0;r<4;r++) acc[dt][r] *= corr[r];
    }
    float rs[4];
    #pragma unroll
    for (int r=0;r<4;r++){
      rs[r] = 0.f;
      #pragma unroll
      for (int su=0;su<4;su++){ s[su][r] = fexp2(s[su][r]-m_[r]); rs[r] += s[su][r]; }
    }
    #pragma unroll
    for (int m=1;m<16;m<<=1)
      #pragma unroll
      for (int r=0;r<4;r++) rs[r] += __shfl_xor(rs[r], m);
    #pragma unroll
    for (int r=0;r<4;r++) l_[r] += rs[r];
    #pragma unroll
    for (int su=0;su<4;su++){
      int kslot = su*2 + (c16>>3);
      #pragma unroll
      for (int r=0;r<4;r++){
        int prow = w*16 + g*4 + r;
        pwb[prow*64 + (kslot ^ (prow&7))*8 + c7] = f2b(s[su][r]);
      }
    }
    int prow = w*16 + c16;
    s16x8 pf0 = *(const s16x8*)&pwb[prow*64 + ((0+g) ^ c7)*8];
    s16x8 pf1 = *(const s16x8*)&pwb[prow*64 + ((4+g) ^ c7)*8];
    __builtin_amdgcn_s_setprio(1);
    #pragma unroll
    for (int dt=0;dt<8;dt++){
      int vrow = dt*16 + c16;
      s16x8 vf0 = *(const s16x8*)&vts[buf][vrow*64 + ((0+g) ^ c7)*8];
      acc[dt] = __builtin_amdgcn_mfma_f32_16x16x32_bf16(pf0, vf0, acc[dt], 0,0,0);
      s16x8 vf1 = *(const s16x8*)&vts[buf][vrow*64 + ((4+g) ^ c7)*8];
      acc[dt] = __builtin_amdgcn_mfma_f32_16x16x32_bf16(pf1, vf1, acc[dt], 0,0,0);
    }
    __builtin_amdgcn_s_setprio(0);
  };

  STAGE(0, 0);
  __syncthreads();
  int cur = 0;
  for (int kb=0; kb<S_TOTC; kb+=64){
    if (kb+64 < S_TOTC) STAGE(cur^1, kb+64);
    COMPUTE(cur);
    __syncthreads();
    cur ^= 1;
  }

  // adapter cross-attention tile (4 valid keys), native exp2, stale rows masked by P=0
  if (tid < 64){
    int row = tid>>4, slot = (tid&15) ^ (row&7);
    *(s16x8*)&kts[0][row*128 + slot*8] = *(const s16x8*)(vdk + (h*4+(tid>>4))*HDM + (tid&15)*8);
  } else if (tid < 192){
    int d = tid - 64;
    int sl0 = (d&7)*8;
    #pragma unroll
    for (int key=0;key<4;key++) vts[0][d*64 + sl0 + key] = vdv[(h*4+key)*HDM + d];
  }
  __syncthreads();
  f32x4 s2 = {0.f,0.f,0.f,0.f};
  #pragma unroll
  for (int kc=0;kc<4;kc++){
    s16x8 kf = *(const s16x8*)&kts[0][c16*128 + ((kc*4+g) ^ c7)*8];
    s2 = __builtin_amdgcn_mfma_f32_16x16x32_bf16(qf[kc], kf, s2, 0,0,0);
  }
  bool valid = (c16 < 4);
  float m2[4], l2[4];
  #pragma unroll
  for (int r=0;r<4;r++) m2[r] = valid? s2[r] : -3e38f;
  #pragma unroll
  for (int m=1;m<16;m<<=1)
    #pragma unroll
    for (int r=0;r<4;r++) m2[r] = fmaxf(m2[r], __shfl_xor(m2[r], m));
  #pragma unroll
  for (int r=0;r<4;r++){ float p = valid? fexp2(s2[r]-m2[r]) : 0.f; s2[r]=p; l2[r]=p; }
  #pragma unroll
  for (int m=1;m<16;m<<=1)
    #pragma unroll
    for (int r=0;r<4;r++) l2[r] += __shfl_xor(l2[r], m);
  #pragma unroll
  for (int r=0;r<4;r++){
    int prow = w*16 + g*4 + r;
    int s0 = (c16>>3) ^ (prow&7);
    int s1 = (2 + (c16>>3)) ^ (prow&7);
    pwb[prow*64 + s0*8 + c7] = f2b(s2[r]);
    pwb[prow*64 + s1*8 + c7] = (u16)0;
  }
  int prow2 = w*16 + c16;
  s16x8 pf2 = *(const s16x8*)&pwb[prow2*64 + (g ^ c7)*8];
  f32x4 a2[8];
  #pragma unroll
  for (int dt=0;dt<8;dt++) a2[dt] = f32x4{0.f,0.f,0.f,0.f};
  #pragma unroll
  for (int dt=0;dt<8;dt++){
    int vrow = dt*16 + c16;
    s16x8 vf = *(const s16x8*)&vts[0][vrow*64 + (g ^ c7)*8];
    a2[dt] = __builtin_amdgcn_mfma_f32_16x16x32_bf16(pf2, vf, a2[dt], 0,0,0);
  }
  float sb = bscale[0];
  float rl[4], rl2[4];
  #pragma unroll
  for (int r=0;r<4;r++){ rl[r] = 1.f/l_[r]; rl2[r] = sb/l2[r]; }
  #pragma unroll
  for (int dt=0;dt<8;dt++)
    #pragma unroll
    for (int r=0;r<4;r++){
      int tok = qb + w*16 + g*4 + r;
      int col = h*HDM + dt*16 + c16;
      hs[(size_t)tok*DM + col] = f2b(acc[dt][r]*rl[r] + a2[dt][r]*rl2[r]);
    }
}

extern "C" void kernel_launch(void* const* d_in, const int* in_sizes, int n_in,
                              void* d_out, int out_size, void* d_ws, size_t ws_size,
                              hipStream_t stream){
  static const int expect[28] = {
    6291456, 1572864, 4096, 327680, 327680,
    9437184, 3072, 9437184, 3072, 9437184, 3072, 128, 128,
    9437184, 3072, 9437184, 3072, 9437184, 3072, 128, 128,
    9437184, 3072, 9437184, 3072, 3145728, 3145728, 1 };
  bool ok = (n_in == 28);
  if (ok) for (int i=0;i<28;i++) if (in_sizes[i] != expect[i]) { ok = false; break; }
  if (!ok){ fillv<<<(out_size+255)/256,256,0,stream>>>((float*)d_out, out_size, 7.0f); return; }
  if (ws_size < 119611392ull){ fillv<<<(out_size+255)/256,256,0,stream>>>((float*)d_out, out_size, 9.0f); return; }

  const float* hidden = (const float*)d_in[0];
  const float* enc    = (const float*)d_in[1];
  const float* adapt  = (const float*)d_in[2];
  const float* fcos   = (const float*)d_in[3];
  const float* fsin   = (const float*)d_in[4];
  const float* Wq  = (const float*)d_in[5];  const float* bq  = (const float*)d_in[6];
  const float* Wk  = (const float*)d_in[7];  const float* bk  = (const float*)d_in[8];
  const float* Wv  = (const float*)d_in[9];  const float* bv  = (const float*)d_in[10];
  const float* nqw = (const float*)d_in[11]; const float* nkw = (const float*)d_in[12];
  const float* Wqa = (const float*)d_in[13]; const float* bqa = (const float*)d_in[14];
  const float* Wka = (const float*)d_in[15]; const float* bka = (const float*)d_in[16];
  const float* Wva = (const float*)d_in[17]; const float* bva = (const float*)d_in[18];
  const float* naq = (const float*)d_in[19]; const float* nak = (const float*)d_in[20];
  const float* Wo  = (const float*)d_in[21]; const float* bo  = (const float*)d_in[22];
  const float* Woa = (const float*)d_in[23]; const float* boa = (const float*)d_in[24];
  const float* Wkad = (const float*)d_in[25]; const float* Wvad = (const float*)d_in[26];
  const float* bsc  = (const float*)d_in[27];
  float* out = (float*)d_out;

  char* ws = (char*)d_ws;
  u16* wt3   = (u16*)(ws);
  u16* kh    = (u16*)(ws);
  u16* vth   = (u16*)(ws + 15728640);
  u16* vdk   = (u16*)(ws + 31457280);
  u16* vdv   = (u16*)(ws + 31481856);
  u16* woaT  = (u16*)(ws + 33554432);
  u16* hbf   = (u16*)(ws + 56623104);
  u16* qh    = (u16*)(ws + 56623104);
  u16* qkvI  = (u16*)(ws + 72351744);
  u16* hsb   = (u16*)(ws + 72351744);
  u16* woT   = (u16*)(ws + 88080384);
  u16* qkvT  = (u16*)(ws + 110100480);
  float* biasA = (float*)(ws + 119537664);
  float* biasB = (float*)(ws + 119574528);

  castbias<<<3912,256,0,stream>>>(hidden, enc, hbf, 786432, 983040,
                                  bq,bk,bv, bqa,bka,bva, biasA);
  ktrans3<<<dim3(48,48,3),256,0,stream>>>(Wq, Wk, Wv, wt3, wt3 + (size_t)DM*DM, wt3 + (size_t)2*DM*DM);
  qkv_gemm<<<dim3(16,72),256,0,stream>>>(hbf, wt3, biasA, qkvI);
  ktrans3<<<dim3(48,48,3),256,0,stream>>>(Wqa, Wka, Wva, wt3, wt3 + (size_t)DM*DM, wt3 + (size_t)2*DM*DM);
  qkv_gemm<<<dim3(4,72),256,0,stream>>>(hbf + (size_t)2048*DM, wt3, biasB, qkvT);
  epi_fused<<<37824,256,0,stream>>>(qkvI, qkvT, nqw,nkw,naq,nak, fcos,fsin, qh, kh, vth,
                                    adapt, Wkad, Wvad, vdk, vdv);
  attnk<<<dim3(20,24),512,0,stream>>>(qh, kh, vth, vdk, vdv, bsc, hsb);
  ktrans3<<<dim3(48,48,2),256,0,stream>>>(Wo, Woa, Woa, woT, woaT, woaT);
  out_gemm<<<dim3(20,24),256,0,stream>>>(hsb, woT, woaT, bo, boa, out);
}

// Round 17
// 671.625 us; speedup vs baseline: 1.0593x; 1.0433x over previous
//
#include <hip/hip_runtime.h>

typedef unsigned short u16;
typedef short s16x8 __attribute__((ext_vector_type(8)));
typedef float f32x4 __attribute__((ext_vector_type(4)));

#define S_TXTC 512
#define S_TOTC 2560
#define DM 3072
#define NH 24
#define HDM 128

__device__ __forceinline__ float b2f(u16 u){ unsigned int i = ((unsigned int)u)<<16; float f; __builtin_memcpy(&f,&i,4); return f; }
__device__ __forceinline__ u16 f2b(float f){ unsigned int i; __builtin_memcpy(&i,&f,4); unsigned int r = i + 0x7FFFu + ((i>>16)&1u); return (u16)(r>>16); }
__device__ __forceinline__ unsigned int pk2(float lo, float hi){
  return (unsigned int)f2b(lo) | ((unsigned int)f2b(hi)<<16);
}
__device__ __forceinline__ s16x8 pk8(float4 a, float4 b){
  s16x8 r;
  r[0]=(short)f2b(a.x); r[1]=(short)f2b(a.y); r[2]=(short)f2b(a.z); r[3]=(short)f2b(a.w);
  r[4]=(short)f2b(b.x); r[5]=(short)f2b(b.y); r[6]=(short)f2b(b.z); r[7]=(short)f2b(b.w);
  return r;
}
__device__ __forceinline__ void g2l16(const void* g, void* l){
  __builtin_amdgcn_global_load_lds((const __attribute__((address_space(1))) void*)g,
                                   (__attribute__((address_space(3))) void*)l, 16, 0, 0);
}
__device__ __forceinline__ float fexp2(float x){ return __builtin_amdgcn_exp2f(x); }  // native v_exp_f32 (2^x)

__global__ __launch_bounds__(256) void fillv(float* __restrict__ p, int n, float v){
  int i = blockIdx.x*256 + threadIdx.x;
  if (i < n) p[i] = v;
}

// ---------------- cast hidden+enc fp32 -> bf16 + concat biases (merged) ----------------
__global__ __launch_bounds__(256) void castbias(const float* __restrict__ a, const float* __restrict__ b,
    u16* __restrict__ dst, int na8, int n8,
    const float* __restrict__ b0, const float* __restrict__ b1, const float* __restrict__ b2,
    const float* __restrict__ c0, const float* __restrict__ c1, const float* __restrict__ c2,
    float* __restrict__ bdst){
  int blk = blockIdx.x;
  if (blk < 3840){
    int i = blk*256 + threadIdx.x;
    if (i >= n8) return;
    const float* src = (i < na8)? a + (size_t)i*8 : b + (size_t)(i-na8)*8;
    float4 f0 = *(const float4*)src;
    float4 f1 = *(const float4*)(src+4);
    *(s16x8*)(dst + (size_t)i*8) = pk8(f0,f1);
  } else {
    int i = (blk-3840)*256 + threadIdx.x;
    if (i >= 18432) return;
    int j = (i < 9216)? i : i - 9216;
    const float* s0 = (i<9216)? b0 : c0; const float* s1 = (i<9216)? b1 : c1; const float* s2 = (i<9216)? b2 : c2;
    bdst[i] = (j<3072)? s0[j] : (j<6144? s1[j-3072] : s2[j-6144]);
  }
}

__global__ __launch_bounds__(256) void ktrans3(const float* __restrict__ W0, const float* __restrict__ W1,
    const float* __restrict__ W2, u16* __restrict__ D0, u16* __restrict__ D1, u16* __restrict__ D2){
  const float* W = (blockIdx.z==0)? W0 : ((blockIdx.z==1)? W1 : W2);
  u16* Wt = (blockIdx.z==0)? D0 : ((blockIdx.z==1)? D1 : D2);
  __shared__ __align__(16) u16 t[64*72];
  int nt = blockIdx.x*64, kt_ = blockIdx.y*64;
  int tid = threadIdx.x;
  #pragma unroll
  for (int i=0;i<2;i++){
    int q = tid + 256*i;
    int r = q>>3, c8 = (q&7)*8;
    float4 f0 = *(const float4*)(W + (size_t)(kt_+r)*DM + nt + c8);
    float4 f1 = *(const float4*)(W + (size_t)(kt_+r)*DM + nt + c8 + 4);
    *(s16x8*)&t[r*72 + c8] = pk8(f0,f1);
  }
  __syncthreads();
  #pragma unroll
  for (int i=0;i<2;i++){
    int q = tid + 256*i;
    int n = q>>3, k8 = (q&7)*8;
    s16x8 v;
    #pragma unroll
    for (int j=0;j<8;j++) v[j] = (short)t[(k8+j)*72 + n];
    *(s16x8*)(Wt + (size_t)(nt+n)*DM + kt_ + k8) = v;
  }
}

// ---------------- m97-style bf16 GEMM core ----------------
template<int OUT32>
__device__ __forceinline__ void gcore(u16* la, u16* lb,
    const u16* __restrict__ A, const u16* __restrict__ Bt,
    const float* __restrict__ bias, void* __restrict__ Cv,
    int ldc, int rb, int crb, int cb){
  const int K = DM;
  int tid = threadIdx.x, w = tid>>6, l = tid&63, g = l>>4, c16 = l&15;
  int wr = (w>>1)*64, wc = (w&1)*64;
  f32x4 acc[4][4] = {};
  const u16* aL = A  + (size_t)(rb + w*32 + (l>>2))*K + (l&3)*8;
  const u16* bL = Bt + (size_t)(cb + w*32 + (l>>2))*K + (l&3)*8;
  u16* laB = la + w*1024;
  u16* lbB = lb + w*1024;
  for (int ks=0; ks<K; ks+=32){
    g2l16(aL + ks,                laB);
    g2l16(aL + 16*(size_t)K + ks, laB + 512);
    g2l16(bL + ks,                lbB);
    g2l16(bL + 16*(size_t)K + ks, lbB + 512);
    __syncthreads();
    s16x8 af[4], bf[4];
    #pragma unroll
    for (int m=0;m<4;m++) af[m] = *(const s16x8*)&la[(wr + m*16 + c16)*32 + g*8];
    #pragma unroll
    for (int n=0;n<4;n++) bf[n] = *(const s16x8*)&lb[(wc + n*16 + c16)*32 + g*8];
    #pragma unroll
    for (int m=0;m<4;m++)
      #pragma unroll
      for (int n=0;n<4;n++)
        acc[m][n] = __builtin_amdgcn_mfma_f32_16x16x32_bf16(af[m], bf[n], acc[m][n], 0,0,0);
    __syncthreads();
  }
  #pragma unroll
  for (int n=0;n<4;n++){
    int col = cb + wc + n*16 + c16;
    float bv = bias[col];
    #pragma unroll
    for (int m=0;m<4;m++){
      int r0 = crb + wr + m*16 + g*4;
      #pragma unroll
      for (int r=0;r<4;r++){
        float oo = acc[m][n][r] + bv;
        if (OUT32) ((float*)Cv)[(size_t)(r0+r)*ldc + col] = oo;
        else       ((u16*)Cv)[(size_t)(r0+r)*ldc + col] = f2b(oo);
      }
    }
  }
}

// XCD-chunked bijective block swizzle (requires nwg % 8 == 0)
__device__ __forceinline__ void xcd_swz(int& bx, int& by){
  int gx = gridDim.x, nwg = gx*gridDim.y;
  int id = blockIdx.y*gx + blockIdx.x;
  int q = nwg>>3;
  int nid = (id&7)*q + (id>>3);
  bx = nid % gx; by = nid / gx;
}

__global__ __launch_bounds__(256) void qkv_gemm(const u16* __restrict__ A, const u16* __restrict__ Bt,
                                                const float* __restrict__ bias, u16* __restrict__ C){
  __shared__ __align__(16) u16 la[4096];
  __shared__ __align__(16) u16 lb[4096];
  int bx, by; xcd_swz(bx, by);
  gcore<0>(la, lb, A, Bt, bias, C, 3*DM, bx*128, bx*128, by*128);
}

__global__ __launch_bounds__(256) void out_gemm(const u16* __restrict__ hsb,
    const u16* __restrict__ woT, const u16* __restrict__ woaT,
    const float* __restrict__ bo, const float* __restrict__ boa, float* __restrict__ out){
  __shared__ __align__(16) u16 la[4096];
  __shared__ __align__(16) u16 lb[4096];
  int bx, by; xcd_swz(bx, by);
  bool txt = (bx < 4);
  int rb = bx*128;
  const u16* Bt = txt? woaT : woT;
  const float* bias = txt? boa : bo;
  float* dst = txt? out + (size_t)2048*DM : out;
  int crb = txt? rb : rb - 512;
  gcore<1>(la, lb, hsb, Bt, bias, dst, DM, rb, crb, by*128);
}

// ---------------- fused epilogues + adapter projections (coalesced) ----------------
// blocks [0,30720): qk RMSNorm+RoPE; [30720,31680): v transpose; [31680,31776): adapter row-sweep GEMV
__global__ __launch_bounds__(256) void epi_fused(
    const u16* __restrict__ qkvI, const u16* __restrict__ qkvT,
    const float* __restrict__ nqw, const float* __restrict__ nkw,
    const float* __restrict__ naq, const float* __restrict__ nak,
    const float* __restrict__ fcos, const float* __restrict__ fsin,
    u16* __restrict__ qh, u16* __restrict__ kh, u16* __restrict__ vt,
    const float* __restrict__ ad, const float* __restrict__ Wkad, const float* __restrict__ Wvad,
    u16* __restrict__ vdk, u16* __restrict__ vdv){
  __shared__ __align__(16) u16 t[64*136];
  int blk = blockIdx.x;
  if (blk < 30720){
    int wid = blk*4 + (threadIdx.x>>6);
    int lane = threadIdx.x&63;
    int which = wid / (NH*S_TOTC);
    int rem = wid % (NH*S_TOTC);
    int h = rem / S_TOTC, tok = rem % S_TOTC;
    const u16* src = ((tok<S_TXTC)? qkvT + (size_t)tok*(3*DM) : qkvI + (size_t)(tok-S_TXTC)*(3*DM))
                     + which*DM + h*HDM;
    const float* nw = which? ((tok<S_TXTC)? nak : nkw) : ((tok<S_TXTC)? naq : nqw);
    int d = lane*2;
    unsigned int u = *(const unsigned int*)(src + d);
    float x0 = b2f((u16)(u&0xffffu)), x1 = b2f((u16)(u>>16));
    float ss = x0*x0 + x1*x1;
    #pragma unroll
    for (int m=1;m<64;m<<=1) ss += __shfl_xor(ss, m);
    float rr = rsqrtf(ss*(1.f/128.f) + 1e-6f);
    float y0 = x0*rr*nw[d];
    float y1 = x1*rr*nw[d+1];
    float2 cc = *(const float2*)(fcos + (size_t)tok*HDM + d);
    float2 sn = *(const float2*)(fsin + (size_t)tok*HDM + d);
    // Q: fold 1/sqrt(HD) * log2(e) so attn softmax runs in exp2 domain
    float sc = which? 1.0f : 0.1275174436f;
    float o0 = (y0*cc.x - y1*sn.x)*sc;
    float o1 = (y1*cc.y + y0*sn.y)*sc;
    u16* dst = (which? kh : qh) + ((size_t)h*S_TOTC + tok)*HDM + d;
    *(unsigned int*)dst = pk2(o0, o1);
  } else if (blk < 31680){
    int bv = blk - 30720;
    int h = bv % NH, tb = bv / NH;
    int tok0 = tb*64, tid = threadIdx.x;
    #pragma unroll
    for (int i=0;i<4;i++){
      int q = tid + 256*i;
      int tr = q>>4, c8 = (q&15)*8;
      int tok = tok0 + tr;
      const u16* src = ((tok<S_TXTC)? qkvT + (size_t)tok*(3*DM) : qkvI + (size_t)(tok-S_TXTC)*(3*DM))
                       + 2*DM + h*HDM;
      *(s16x8*)&t[tr*136 + c8] = *(const s16x8*)(src + c8);
    }
    __syncthreads();
    #pragma unroll
    for (int i=0;i<4;i++){
      int q = tid + 256*i;
      int d = q>>3, j8 = (q&7)*8;
      s16x8 v;
      #pragma unroll
      for (int j=0;j<8;j++) v[j] = (short)t[(j8+j)*136 + d];
      *(s16x8*)(vt + ((size_t)h*HDM + d)*S_TOTC + tok0 + j8) = v;
    }
  } else {
    // adapter: 96 blocks = 2 tensors x 48 col-strips of 64; lanes sweep W rows (coalesced)
    int bv = blk - 31680;
    int tensor = bv / 48;
    int col = (bv % 48)*64 + (threadIdx.x & 63);
    int tok = threadIdx.x >> 6;
    const float* Wp = tensor? Wvad : Wkad;
    const float* arow = ad + tok*1024;
    float s = 0.f;
    #pragma unroll 4
    for (int k=0;k<1024;k++)
      s += arow[k] * Wp[(size_t)k*DM + col];
    int hh = col>>7, d = col&127;
    (tensor? vdv : vdk)[(hh*4+tok)*HDM + d] = f2b(s);
  }
}

// ---------------- attn: QBLK=128, 8 waves, KVBLK=64, g2l16 dbuf, native-exp2 softmax ----------------
__global__ __launch_bounds__(512,2) void attnk(const u16* __restrict__ qh, const u16* __restrict__ kh,
    const u16* __restrict__ vt, const u16* __restrict__ vdk, const u16* __restrict__ vdv,
    const float* __restrict__ bscale, u16* __restrict__ hs){
  __shared__ __align__(16) u16 kts[2][64*128];   // [key][d], slot ^= row&7 (via pre-swizzled source)
  __shared__ __align__(16) u16 vts[2][128*64];   // [d][key], slot ^= row&7
  __shared__ __align__(16) u16 pwb[128*64];      // [q][key], slot ^= row&7 (wave-private rows)
  int h = blockIdx.y, qb = blockIdx.x*128;
  int tid = threadIdx.x, w = tid>>6, l = tid&63, g = l>>4, c16 = l&15;
  int qrow = qb + w*16 + c16;
  int c7 = c16&7;
  s16x8 qf[4];
  #pragma unroll
  for (int kc=0;kc<4;kc++) qf[kc] = *(const s16x8*)(qh + ((size_t)h*S_TOTC + qrow)*HDM + kc*32 + g*8);
  f32x4 acc[8];
  #pragma unroll
  for (int dt=0;dt<8;dt++) acc[dt] = f32x4{0.f,0.f,0.f,0.f};
  float m_[4] = {-3e38f,-3e38f,-3e38f,-3e38f};
  float l_[4] = {0.f,0.f,0.f,0.f};
  const u16* khB = kh + (size_t)h*S_TOTC*HDM;
  const u16* vtB = vt + (size_t)h*HDM*S_TOTC;

  auto STAGE = [&](int buf, int kb){
    #pragma unroll
    for (int c=0;c<2;c++){
      int krow = w*8 + c*4 + (l>>4);
      int kchunk = (l&15) ^ (krow&7);
      g2l16(khB + (size_t)(kb + krow)*HDM + kchunk*8, &kts[buf][w*1024 + c*512]);
      int vrow = w*16 + c*8 + (l>>3);
      int vchunk = (l&7) ^ (vrow&7);
      g2l16(vtB + (size_t)vrow*S_TOTC + kb + vchunk*8, &vts[buf][w*1024 + c*512]);
    }
  };
  auto COMPUTE = [&](int buf){
    f32x4 s[4];
    #pragma unroll
    for (int su=0;su<4;su++) s[su] = f32x4{0.f,0.f,0.f,0.f};
    __builtin_amdgcn_s_setprio(1);
    #pragma unroll
    for (int su=0;su<4;su++)
      #pragma unroll
      for (int kc=0;kc<4;kc++){
        s16x8 kf = *(const s16x8*)&kts[buf][(su*16+c16)*128 + ((kc*4+g) ^ c7)*8];
        s[su] = __builtin_amdgcn_mfma_f32_16x16x32_bf16(qf[kc], kf, s[su], 0,0,0);
      }
    __builtin_amdgcn_s_setprio(0);
    float tm[4];
    #pragma unroll
    for (int r=0;r<4;r++)
      tm[r] = fmaxf(fmaxf(s[0][r],s[1][r]), fmaxf(s[2][r],s[3][r]));
    #pragma unroll
    for (int m=1;m<16;m<<=1)
      #pragma unroll
      for (int r=0;r<4;r++) tm[r] = fmaxf(tm[r], __shfl_xor(tm[r], m));
    bool need = !__all(tm[0]<=m_[0]+11.5415603f && tm[1]<=m_[1]+11.5415603f &&
                       tm[2]<=m_[2]+11.5415603f && tm[3]<=m_[3]+11.5415603f);
    if (need){
      float corr[4];
      #pragma unroll
      for (int r=0;r<4;r++){
        float mn = fmaxf(m_[r], tm[r]);
        corr[r] = fexp2(m_[r]-mn);
        m_[r] = mn;
        l_[r] *= corr[r];
      }
      #pragma unroll
      for (int dt=0;dt<8;dt++)
        #pragma unroll
        for (int r=0;r<4;r++) acc[dt][r] *= corr[r];
    }
    float rs[4];
    #pragma unroll
    for (int r=0;r<4;r++){
      rs[r] = 0.f;
      #pragma unroll
      for (int su=0;su<4;su++){ s[su][r] = fexp2(s[su][r]-m_[r]); rs[r] += s[su][r]; }
    }
    #pragma unroll
    for (int m=1;m<16;m<<=1)
      #pragma unroll
      for (int r=0;r<4;r++) rs[r] += __shfl_xor(rs[r], m);
    #pragma unroll
    for (int r=0;r<4;r++) l_[r] += rs[r];
    #pragma unroll
    for (int su=0;su<4;su++){
      int kslot = su*2 + (c16>>3);
      #pragma unroll
      for (int r=0;r<4;r++){
        int prow = w*16 + g*4 + r;
        pwb[prow*64 + (kslot ^ (prow&7))*8 + c7] = f2b(s[su][r]);
      }
    }
    int prow = w*16 + c16;
    s16x8 pf0 = *(const s16x8*)&pwb[prow*64 + ((0+g) ^ c7)*8];
    s16x8 pf1 = *(const s16x8*)&pwb[prow*64 + ((4+g) ^ c7)*8];
    __builtin_amdgcn_s_setprio(1);
    #pragma unroll
    for (int dt=0;dt<8;dt++){
      int vrow = dt*16 + c16;
      s16x8 vf0 = *(const s16x8*)&vts[buf][vrow*64 + ((0+g) ^ c7)*8];
      acc[dt] = __builtin_amdgcn_mfma_f32_16x16x32_bf16(pf0, vf0, acc[dt], 0,0,0);
      s16x8 vf1 = *(const s16x8*)&vts[buf][vrow*64 + ((4+g) ^ c7)*8];
      acc[dt] = __builtin_amdgcn_mfma_f32_16x16x32_bf16(pf1, vf1, acc[dt], 0,0,0);
    }
    __builtin_amdgcn_s_setprio(0);
  };

  STAGE(0, 0);
  __syncthreads();
  int cur = 0;
  for (int kb=0; kb<S_TOTC; kb+=64){
    if (kb+64 < S_TOTC) STAGE(cur^1, kb+64);
    COMPUTE(cur);
    __syncthreads();
    cur ^= 1;
  }

  // adapter cross-attention tile (4 valid keys), native exp2, stale rows masked by P=0
  if (tid < 64){
    int row = tid>>4, slot = (tid&15) ^ (row&7);
    *(s16x8*)&kts[0][row*128 + slot*8] = *(const s16x8*)(vdk + (h*4+(tid>>4))*HDM + (tid&15)*8);
  } else if (tid < 192){
    int d = tid - 64;
    int sl0 = (d&7)*8;
    #pragma unroll
    for (int key=0;key<4;key++) vts[0][d*64 + sl0 + key] = vdv[(h*4+key)*HDM + d];
  }
  __syncthreads();
  f32x4 s2 = {0.f,0.f,0.f,0.f};
  #pragma unroll
  for (int kc=0;kc<4;kc++){
    s16x8 kf = *(const s16x8*)&kts[0][c16*128 + ((kc*4+g) ^ c7)*8];
    s2 = __builtin_amdgcn_mfma_f32_16x16x32_bf16(qf[kc], kf, s2, 0,0,0);
  }
  bool valid = (c16 < 4);
  float m2[4], l2[4];
  #pragma unroll
  for (int r=0;r<4;r++) m2[r] = valid? s2[r] : -3e38f;
  #pragma unroll
  for (int m=1;m<16;m<<=1)
    #pragma unroll
    for (int r=0;r<4;r++) m2[r] = fmaxf(m2[r], __shfl_xor(m2[r], m));
  #pragma unroll
  for (int r=0;r<4;r++){ float p = valid? fexp2(s2[r]-m2[r]) : 0.f; s2[r]=p; l2[r]=p; }
  #pragma unroll
  for (int m=1;m<16;m<<=1)
    #pragma unroll
    for (int r=0;r<4;r++) l2[r] += __shfl_xor(l2[r], m);
  #pragma unroll
  for (int r=0;r<4;r++){
    int prow = w*16 + g*4 + r;
    int s0 = (c16>>3) ^ (prow&7);
    int s1 = (2 + (c16>>3)) ^ (prow&7);
    pwb[prow*64 + s0*8 + c7] = f2b(s2[r]);
    pwb[prow*64 + s1*8 + c7] = (u16)0;
  }
  int prow2 = w*16 + c16;
  s16x8 pf2 = *(const s16x8*)&pwb[prow2*64 + (g ^ c7)*8];
  f32x4 a2[8];
  #pragma unroll
  for (int dt=0;dt<8;dt++) a2[dt] = f32x4{0.f,0.f,0.f,0.f};
  #pragma unroll
  for (int dt=0;dt<8;dt++){
    int vrow = dt*16 + c16;
    s16x8 vf = *(const s16x8*)&vts[0][vrow*64 + (g ^ c7)*8];
    a2[dt] = __builtin_amdgcn_mfma_f32_16x16x32_bf16(pf2, vf, a2[dt], 0,0,0);
  }
  float sb = bscale[0];
  float rl[4], rl2[4];
  #pragma unroll
  for (int r=0;r<4;r++){ rl[r] = 1.f/l_[r]; rl2[r] = sb/l2[r]; }
  #pragma unroll
  for (int dt=0;dt<8;dt++)
    #pragma unroll
    for (int r=0;r<4;r++){
      int tok = qb + w*16 + g*4 + r;
      int col = h*HDM + dt*16 + c16;
      hs[(size_t)tok*DM + col] = f2b(acc[dt][r]*rl[r] + a2[dt][r]*rl2[r]);
    }
}

extern "C" void kernel_launch(void* const* d_in, const int* in_sizes, int n_in,
                              void* d_out, int out_size, void* d_ws, size_t ws_size,
                              hipStream_t stream){
  static const int expect[28] = {
    6291456, 1572864, 4096, 327680, 327680,
    9437184, 3072, 9437184, 3072, 9437184, 3072, 128, 128,
    9437184, 3072, 9437184, 3072, 9437184, 3072, 128, 128,
    9437184, 3072, 9437184, 3072, 3145728, 3145728, 1 };
  bool ok = (n_in == 28);
  if (ok) for (int i=0;i<28;i++) if (in_sizes[i] != expect[i]) { ok = false; break; }
  if (!ok){ fillv<<<(out_size+255)/256,256,0,stream>>>((float*)d_out, out_size, 7.0f); return; }
  if (ws_size < 119611392ull){ fillv<<<(out_size+255)/256,256,0,stream>>>((float*)d_out, out_size, 9.0f); return; }

  const float* hidden = (const float*)d_in[0];
  const float* enc    = (const float*)d_in[1];
  const float* adapt  = (const float*)d_in[2];
  const float* fcos   = (const float*)d_in[3];
  const float* fsin   = (const float*)d_in[4];
  const float* Wq  = (const float*)d_in[5];  const float* bq  = (const float*)d_in[6];
  const float* Wk  = (const float*)d_in[7];  const float* bk  = (const float*)d_in[8];
  const float* Wv  = (const float*)d_in[9];  const float* bv  = (const float*)d_in[10];
  const float* nqw = (const float*)d_in[11]; const float* nkw = (const float*)d_in[12];
  const float* Wqa = (const float*)d_in[13]; const float* bqa = (const float*)d_in[14];
  const float* Wka = (const float*)d_in[15]; const float* bka = (const float*)d_in[16];
  const float* Wva = (const float*)d_in[17]; const float* bva = (const float*)d_in[18];
  const float* naq = (const float*)d_in[19]; const float* nak = (const float*)d_in[20];
  const float* Wo  = (const float*)d_in[21]; const float* bo  = (const float*)d_in[22];
  const float* Woa = (const float*)d_in[23]; const float* boa = (const float*)d_in[24];
  const float* Wkad = (const float*)d_in[25]; const float* Wvad = (const float*)d_in[26];
  const float* bsc  = (const float*)d_in[27];
  float* out = (float*)d_out;

  char* ws = (char*)d_ws;
  u16* wt3   = (u16*)(ws);
  u16* kh    = (u16*)(ws);
  u16* vth   = (u16*)(ws + 15728640);
  u16* vdk   = (u16*)(ws + 31457280);
  u16* vdv   = (u16*)(ws + 31481856);
  u16* woaT  = (u16*)(ws + 33554432);
  u16* hbf   = (u16*)(ws + 56623104);
  u16* qh    = (u16*)(ws + 56623104);
  u16* qkvI  = (u16*)(ws + 72351744);
  u16* hsb   = (u16*)(ws + 72351744);
  u16* woT   = (u16*)(ws + 88080384);
  u16* qkvT  = (u16*)(ws + 110100480);
  float* biasA = (float*)(ws + 119537664);
  float* biasB = (float*)(ws + 119574528);

  castbias<<<3912,256,0,stream>>>(hidden, enc, hbf, 786432, 983040,
                                  bq,bk,bv, bqa,bka,bva, biasA);
  ktrans3<<<dim3(48,48,3),256,0,stream>>>(Wq, Wk, Wv, wt3, wt3 + (size_t)DM*DM, wt3 + (size_t)2*DM*DM);
  qkv_gemm<<<dim3(16,72),256,0,stream>>>(hbf, wt3, biasA, qkvI);
  ktrans3<<<dim3(48,48,3),256,0,stream>>>(Wqa, Wka, Wva, wt3, wt3 + (size_t)DM*DM, wt3 + (size_t)2*DM*DM);
  qkv_gemm<<<dim3(4,72),256,0,stream>>>(hbf + (size_t)2048*DM, wt3, biasB, qkvT);
  epi_fused<<<31776,256,0,stream>>>(qkvI, qkvT, nqw,nkw,naq,nak, fcos,fsin, qh, kh, vth,
                                    adapt, Wkad, Wvad, vdk, vdv);
  attnk<<<dim3(20,24),512,0,stream>>>(qh, kh, vth, vdk, vdv, bsc, hsb);
  ktrans3<<<dim3(48,48,2),256,0,stream>>>(Wo, Woa, Woa, woT, woaT, woaT);
  out_gemm<<<dim3(20,24),256,0,stream>>>(hsb, woT, woaT, bo, boa, out);
}

// Round 18
// 666.592 us; speedup vs baseline: 1.0673x; 1.0075x over previous
//
#include <hip/hip_runtime.h>

typedef unsigned short u16;
typedef short s16x8 __attribute__((ext_vector_type(8)));
typedef float f32x4 __attribute__((ext_vector_type(4)));

#define S_TXTC 512
#define S_TOTC 2560
#define DM 3072
#define NH 24
#define HDM 128

__device__ __forceinline__ float b2f(u16 u){ unsigned int i = ((unsigned int)u)<<16; float f; __builtin_memcpy(&f,&i,4); return f; }
__device__ __forceinline__ u16 f2b(float f){ unsigned int i; __builtin_memcpy(&i,&f,4); unsigned int r = i + 0x7FFFu + ((i>>16)&1u); return (u16)(r>>16); }
__device__ __forceinline__ unsigned int pk2(float lo, float hi){
  return (unsigned int)f2b(lo) | ((unsigned int)f2b(hi)<<16);
}
__device__ __forceinline__ s16x8 pk8(float4 a, float4 b){
  s16x8 r;
  r[0]=(short)f2b(a.x); r[1]=(short)f2b(a.y); r[2]=(short)f2b(a.z); r[3]=(short)f2b(a.w);
  r[4]=(short)f2b(b.x); r[5]=(short)f2b(b.y); r[6]=(short)f2b(b.z); r[7]=(short)f2b(b.w);
  return r;
}
__device__ __forceinline__ void g2l16(const void* g, void* l){
  __builtin_amdgcn_global_load_lds((const __attribute__((address_space(1))) void*)g,
                                   (__attribute__((address_space(3))) void*)l, 16, 0, 0);
}
__device__ __forceinline__ float fexp2(float x){ return __builtin_amdgcn_exp2f(x); }  // native v_exp_f32 (2^x)

__global__ __launch_bounds__(256) void fillv(float* __restrict__ p, int n, float v){
  int i = blockIdx.x*256 + threadIdx.x;
  if (i < n) p[i] = v;
}

// ---------------- cast hidden+enc fp32 -> bf16 + concat biases (merged) ----------------
__global__ __launch_bounds__(256) void castbias(const float* __restrict__ a, const float* __restrict__ b,
    u16* __restrict__ dst, int na8, int n8,
    const float* __restrict__ b0, const float* __restrict__ b1, const float* __restrict__ b2,
    const float* __restrict__ c0, const float* __restrict__ c1, const float* __restrict__ c2,
    float* __restrict__ bdst){
  int blk = blockIdx.x;
  if (blk < 3840){
    int i = blk*256 + threadIdx.x;
    if (i >= n8) return;
    const float* src = (i < na8)? a + (size_t)i*8 : b + (size_t)(i-na8)*8;
    float4 f0 = *(const float4*)src;
    float4 f1 = *(const float4*)(src+4);
    *(s16x8*)(dst + (size_t)i*8) = pk8(f0,f1);
  } else {
    int i = (blk-3840)*256 + threadIdx.x;
    if (i >= 18432) return;
    int j = (i < 9216)? i : i - 9216;
    const float* s0 = (i<9216)? b0 : c0; const float* s1 = (i<9216)? b1 : c1; const float* s2 = (i<9216)? b2 : c2;
    bdst[i] = (j<3072)? s0[j] : (j<6144? s1[j-3072] : s2[j-6144]);
  }
}

__global__ __launch_bounds__(256) void ktrans3(const float* __restrict__ W0, const float* __restrict__ W1,
    const float* __restrict__ W2, u16* __restrict__ D0, u16* __restrict__ D1, u16* __restrict__ D2){
  const float* W = (blockIdx.z==0)? W0 : ((blockIdx.z==1)? W1 : W2);
  u16* Wt = (blockIdx.z==0)? D0 : ((blockIdx.z==1)? D1 : D2);
  __shared__ __align__(16) u16 t[64*72];
  int nt = blockIdx.x*64, kt_ = blockIdx.y*64;
  int tid = threadIdx.x;
  #pragma unroll
  for (int i=0;i<2;i++){
    int q = tid + 256*i;
    int r = q>>3, c8 = (q&7)*8;
    float4 f0 = *(const float4*)(W + (size_t)(kt_+r)*DM + nt + c8);
    float4 f1 = *(const float4*)(W + (size_t)(kt_+r)*DM + nt + c8 + 4);
    *(s16x8*)&t[r*72 + c8] = pk8(f0,f1);
  }
  __syncthreads();
  #pragma unroll
  for (int i=0;i<2;i++){
    int q = tid + 256*i;
    int n = q>>3, k8 = (q&7)*8;
    s16x8 v;
    #pragma unroll
    for (int j=0;j<8;j++) v[j] = (short)t[(k8+j)*72 + n];
    *(s16x8*)(Wt + (size_t)(nt+n)*DM + kt_ + k8) = v;
  }
}

// ---------------- m97-style bf16 GEMM core ----------------
template<int OUT32>
__device__ __forceinline__ void gcore(u16* la, u16* lb,
    const u16* __restrict__ A, const u16* __restrict__ Bt,
    const float* __restrict__ bias, void* __restrict__ Cv,
    int ldc, int rb, int crb, int cb){
  const int K = DM;
  int tid = threadIdx.x, w = tid>>6, l = tid&63, g = l>>4, c16 = l&15;
  int wr = (w>>1)*64, wc = (w&1)*64;
  f32x4 acc[4][4] = {};
  const u16* aL = A  + (size_t)(rb + w*32 + (l>>2))*K + (l&3)*8;
  const u16* bL = Bt + (size_t)(cb + w*32 + (l>>2))*K + (l&3)*8;
  u16* laB = la + w*1024;
  u16* lbB = lb + w*1024;
  for (int ks=0; ks<K; ks+=32){
    g2l16(aL + ks,                laB);
    g2l16(aL + 16*(size_t)K + ks, laB + 512);
    g2l16(bL + ks,                lbB);
    g2l16(bL + 16*(size_t)K + ks, lbB + 512);
    __syncthreads();
    s16x8 af[4], bf[4];
    #pragma unroll
    for (int m=0;m<4;m++) af[m] = *(const s16x8*)&la[(wr + m*16 + c16)*32 + g*8];
    #pragma unroll
    for (int n=0;n<4;n++) bf[n] = *(const s16x8*)&lb[(wc + n*16 + c16)*32 + g*8];
    #pragma unroll
    for (int m=0;m<4;m++)
      #pragma unroll
      for (int n=0;n<4;n++)
        acc[m][n] = __builtin_amdgcn_mfma_f32_16x16x32_bf16(af[m], bf[n], acc[m][n], 0,0,0);
    __syncthreads();
  }
  #pragma unroll
  for (int n=0;n<4;n++){
    int col = cb + wc + n*16 + c16;
    float bv = bias[col];
    #pragma unroll
    for (int m=0;m<4;m++){
      int r0 = crb + wr + m*16 + g*4;
      #pragma unroll
      for (int r=0;r<4;r++){
        float oo = acc[m][n][r] + bv;
        if (OUT32) ((float*)Cv)[(size_t)(r0+r)*ldc + col] = oo;
        else       ((u16*)Cv)[(size_t)(r0+r)*ldc + col] = f2b(oo);
      }
    }
  }
}

// XCD-chunked bijective block swizzle (requires nwg % 8 == 0)
__device__ __forceinline__ void xcd_swz(int& bx, int& by){
  int gx = gridDim.x, nwg = gx*gridDim.y;
  int id = blockIdx.y*gx + blockIdx.x;
  int q = nwg>>3;
  int nid = (id&7)*q + (id>>3);
  bx = nid % gx; by = nid / gx;
}

__global__ __launch_bounds__(256) void qkv_gemm(const u16* __restrict__ A, const u16* __restrict__ Bt,
                                                const float* __restrict__ bias, u16* __restrict__ C){
  __shared__ __align__(16) u16 la[4096];
  __shared__ __align__(16) u16 lb[4096];
  int bx, by; xcd_swz(bx, by);
  gcore<0>(la, lb, A, Bt, bias, C, 3*DM, bx*128, bx*128, by*128);
}

__global__ __launch_bounds__(256) void out_gemm(const u16* __restrict__ hsb,
    const u16* __restrict__ woT, const u16* __restrict__ woaT,
    const float* __restrict__ bo, const float* __restrict__ boa, float* __restrict__ out){
  __shared__ __align__(16) u16 la[4096];
  __shared__ __align__(16) u16 lb[4096];
  int bx, by; xcd_swz(bx, by);
  bool txt = (bx < 4);
  int rb = bx*128;
  const u16* Bt = txt? woaT : woT;
  const float* bias = txt? boa : bo;
  float* dst = txt? out + (size_t)2048*DM : out;
  int crb = txt? rb : rb - 512;
  gcore<1>(la, lb, hsb, Bt, bias, dst, DM, rb, crb, by*128);
}

// ---------------- fused epilogues + adapter projections ----------------
// blocks [0,15360): qk RMSNorm+RoPE (2 rows/wave, 32 lanes/row, 4 elems/lane);
// [15360,16320): v transpose; [16320,16416): adapter row-sweep GEMV
__global__ __launch_bounds__(256) void epi_fused(
    const u16* __restrict__ qkvI, const u16* __restrict__ qkvT,
    const float* __restrict__ nqw, const float* __restrict__ nkw,
    const float* __restrict__ naq, const float* __restrict__ nak,
    const float* __restrict__ fcos, const float* __restrict__ fsin,
    u16* __restrict__ qh, u16* __restrict__ kh, u16* __restrict__ vt,
    const float* __restrict__ ad, const float* __restrict__ Wkad, const float* __restrict__ Wvad,
    u16* __restrict__ vdk, u16* __restrict__ vdv){
  __shared__ __align__(16) u16 t[64*136];
  int blk = blockIdx.x;
  if (blk < 15360){
    int lane = threadIdx.x&63;
    int rowid = blk*8 + (threadIdx.x>>6)*2 + (lane>>5);
    int which = rowid / (NH*S_TOTC);
    int rem = rowid % (NH*S_TOTC);
    int h = rem / S_TOTC, tok = rem % S_TOTC;
    const u16* src = ((tok<S_TXTC)? qkvT + (size_t)tok*(3*DM) : qkvI + (size_t)(tok-S_TXTC)*(3*DM))
                     + which*DM + h*HDM;
    const float* nw = which? ((tok<S_TXTC)? nak : nkw) : ((tok<S_TXTC)? naq : nqw);
    int d = (lane&31)*4;
    uint2 u = *(const uint2*)(src + d);
    float x0 = b2f((u16)(u.x&0xffffu)), x1 = b2f((u16)(u.x>>16));
    float x2 = b2f((u16)(u.y&0xffffu)), x3 = b2f((u16)(u.y>>16));
    float ss = x0*x0 + x1*x1 + x2*x2 + x3*x3;
    #pragma unroll
    for (int m=1;m<32;m<<=1) ss += __shfl_xor(ss, m);
    float rr = rsqrtf(ss*(1.f/128.f) + 1e-6f);
    float4 nv = *(const float4*)(nw + d);
    float y0 = x0*rr*nv.x, y1 = x1*rr*nv.y, y2 = x2*rr*nv.z, y3 = x3*rr*nv.w;
    float4 cc = *(const float4*)(fcos + (size_t)tok*HDM + d);
    float4 sn = *(const float4*)(fsin + (size_t)tok*HDM + d);
    // Q: fold 1/sqrt(HD) * log2(e) so attn softmax runs in exp2 domain
    float sc = which? 1.0f : 0.1275174436f;
    float o0 = (y0*cc.x - y1*sn.x)*sc;
    float o1 = (y1*cc.y + y0*sn.y)*sc;
    float o2 = (y2*cc.z - y3*sn.z)*sc;
    float o3 = (y3*cc.w + y2*sn.w)*sc;
    u16* dst = (which? kh : qh) + ((size_t)h*S_TOTC + tok)*HDM + d;
    uint2 ov; ov.x = pk2(o0,o1); ov.y = pk2(o2,o3);
    *(uint2*)dst = ov;
  } else if (blk < 16320){
    int bv = blk - 15360;
    int h = bv % NH, tb = bv / NH;
    int tok0 = tb*64, tid = threadIdx.x;
    #pragma unroll
    for (int i=0;i<4;i++){
      int q = tid + 256*i;
      int tr = q>>4, c8 = (q&15)*8;
      int tok = tok0 + tr;
      const u16* src = ((tok<S_TXTC)? qkvT + (size_t)tok*(3*DM) : qkvI + (size_t)(tok-S_TXTC)*(3*DM))
                       + 2*DM + h*HDM;
      *(s16x8*)&t[tr*136 + c8] = *(const s16x8*)(src + c8);
    }
    __syncthreads();
    #pragma unroll
    for (int i=0;i<4;i++){
      int q = tid + 256*i;
      int d = q>>3, j8 = (q&7)*8;
      s16x8 v;
      #pragma unroll
      for (int j=0;j<8;j++) v[j] = (short)t[(j8+j)*136 + d];
      *(s16x8*)(vt + ((size_t)h*HDM + d)*S_TOTC + tok0 + j8) = v;
    }
  } else {
    // adapter: 96 blocks = 2 tensors x 48 col-strips of 64; lanes sweep W rows (coalesced)
    int bv = blk - 16320;
    int tensor = bv / 48;
    int col = (bv % 48)*64 + (threadIdx.x & 63);
    int tok = threadIdx.x >> 6;
    const float* Wp = tensor? Wvad : Wkad;
    const float* arow = ad + tok*1024;
    float s = 0.f;
    #pragma unroll 4
    for (int k=0;k<1024;k++)
      s += arow[k] * Wp[(size_t)k*DM + col];
    int hh = col>>7, d = col&127;
    (tensor? vdv : vdk)[(hh*4+tok)*HDM + d] = f2b(s);
  }
}

// ---------------- attn: QBLK=128, 8 waves, KVBLK=64, g2l16 dbuf, native-exp2 softmax, no setprio ----------------
__global__ __launch_bounds__(512,2) void attnk(const u16* __restrict__ qh, const u16* __restrict__ kh,
    const u16* __restrict__ vt, const u16* __restrict__ vdk, const u16* __restrict__ vdv,
    const float* __restrict__ bscale, u16* __restrict__ hs){
  __shared__ __align__(16) u16 kts[2][64*128];   // [key][d], slot ^= row&7 (via pre-swizzled source)
  __shared__ __align__(16) u16 vts[2][128*64];   // [d][key], slot ^= row&7
  __shared__ __align__(16) u16 pwb[128*64];      // [q][key], slot ^= row&7 (wave-private rows)
  int h = blockIdx.y, qb = blockIdx.x*128;
  int tid = threadIdx.x, w = tid>>6, l = tid&63, g = l>>4, c16 = l&15;
  int qrow = qb + w*16 + c16;
  int c7 = c16&7;
  s16x8 qf[4];
  #pragma unroll
  for (int kc=0;kc<4;kc++) qf[kc] = *(const s16x8*)(qh + ((size_t)h*S_TOTC + qrow)*HDM + kc*32 + g*8);
  f32x4 acc[8];
  #pragma unroll
  for (int dt=0;dt<8;dt++) acc[dt] = f32x4{0.f,0.f,0.f,0.f};
  float m_[4] = {-3e38f,-3e38f,-3e38f,-3e38f};
  float l_[4] = {0.f,0.f,0.f,0.f};
  const u16* khB = kh + (size_t)h*S_TOTC*HDM;
  const u16* vtB = vt + (size_t)h*HDM*S_TOTC;

  auto STAGE = [&](int buf, int kb){
    #pragma unroll
    for (int c=0;c<2;c++){
      int krow = w*8 + c*4 + (l>>4);
      int kchunk = (l&15) ^ (krow&7);
      g2l16(khB + (size_t)(kb + krow)*HDM + kchunk*8, &kts[buf][w*1024 + c*512]);
      int vrow = w*16 + c*8 + (l>>3);
      int vchunk = (l&7) ^ (vrow&7);
      g2l16(vtB + (size_t)vrow*S_TOTC + kb + vchunk*8, &vts[buf][w*1024 + c*512]);
    }
  };
  auto COMPUTE = [&](int buf){
    f32x4 s[4];
    #pragma unroll
    for (int su=0;su<4;su++) s[su] = f32x4{0.f,0.f,0.f,0.f};
    #pragma unroll
    for (int su=0;su<4;su++)
      #pragma unroll
      for (int kc=0;kc<4;kc++){
        s16x8 kf = *(const s16x8*)&kts[buf][(su*16+c16)*128 + ((kc*4+g) ^ c7)*8];
        s[su] = __builtin_amdgcn_mfma_f32_16x16x32_bf16(qf[kc], kf, s[su], 0,0,0);
      }
    float tm[4];
    #pragma unroll
    for (int r=0;r<4;r++)
      tm[r] = fmaxf(fmaxf(s[0][r],s[1][r]), fmaxf(s[2][r],s[3][r]));
    #pragma unroll
    for (int m=1;m<16;m<<=1)
      #pragma unroll
      for (int r=0;r<4;r++) tm[r] = fmaxf(tm[r], __shfl_xor(tm[r], m));
    bool need = !__all(tm[0]<=m_[0]+11.5415603f && tm[1]<=m_[1]+11.5415603f &&
                       tm[2]<=m_[2]+11.5415603f && tm[3]<=m_[3]+11.5415603f);
    if (need){
      float corr[4];
      #pragma unroll
      for (int r=0;r<4;r++){
        float mn = fmaxf(m_[r], tm[r]);
        corr[r] = fexp2(m_[r]-mn);
        m_[r] = mn;
        l_[r] *= corr[r];
      }
      #pragma unroll
      for (int dt=0;dt<8;dt++)
        #pragma unroll
        for (int r=0;r<4;r++) acc[dt][r] *= corr[r];
    }
    float rs[4];
    #pragma unroll
    for (int r=0;r<4;r++){
      rs[r] = 0.f;
      #pragma unroll
      for (int su=0;su<4;su++){ s[su][r] = fexp2(s[su][r]-m_[r]); rs[r] += s[su][r]; }
    }
    #pragma unroll
    for (int m=1;m<16;m<<=1)
      #pragma unroll
      for (int r=0;r<4;r++) rs[r] += __shfl_xor(rs[r], m);
    #pragma unroll
    for (int r=0;r<4;r++) l_[r] += rs[r];
    #pragma unroll
    for (int su=0;su<4;su++){
      int kslot = su*2 + (c16>>3);
      #pragma unroll
      for (int r=0;r<4;r++){
        int prow = w*16 + g*4 + r;
        pwb[prow*64 + (kslot ^ (prow&7))*8 + c7] = f2b(s[su][r]);
      }
    }
    int prow = w*16 + c16;
    s16x8 pf0 = *(const s16x8*)&pwb[prow*64 + ((0+g) ^ c7)*8];
    s16x8 pf1 = *(const s16x8*)&pwb[prow*64 + ((4+g) ^ c7)*8];
    #pragma unroll
    for (int dt=0;dt<8;dt++){
      int vrow = dt*16 + c16;
      s16x8 vf0 = *(const s16x8*)&vts[buf][vrow*64 + ((0+g) ^ c7)*8];
      acc[dt] = __builtin_amdgcn_mfma_f32_16x16x32_bf16(pf0, vf0, acc[dt], 0,0,0);
      s16x8 vf1 = *(const s16x8*)&vts[buf][vrow*64 + ((4+g) ^ c7)*8];
      acc[dt] = __builtin_amdgcn_mfma_f32_16x16x32_bf16(pf1, vf1, acc[dt], 0,0,0);
    }
  };

  STAGE(0, 0);
  __syncthreads();
  int cur = 0;
  for (int kb=0; kb<S_TOTC; kb+=64){
    if (kb+64 < S_TOTC) STAGE(cur^1, kb+64);
    COMPUTE(cur);
    __syncthreads();
    cur ^= 1;
  }

  // adapter cross-attention tile (4 valid keys), native exp2, stale rows masked by P=0
  if (tid < 64){
    int row = tid>>4, slot = (tid&15) ^ (row&7);
    *(s16x8*)&kts[0][row*128 + slot*8] = *(const s16x8*)(vdk + (h*4+(tid>>4))*HDM + (tid&15)*8);
  } else if (tid < 192){
    int d = tid - 64;
    int sl0 = (d&7)*8;
    #pragma unroll
    for (int key=0;key<4;key++) vts[0][d*64 + sl0 + key] = vdv[(h*4+key)*HDM + d];
  }
  __syncthreads();
  f32x4 s2 = {0.f,0.f,0.f,0.f};
  #pragma unroll
  for (int kc=0;kc<4;kc++){
    s16x8 kf = *(const s16x8*)&kts[0][c16*128 + ((kc*4+g) ^ c7)*8];
    s2 = __builtin_amdgcn_mfma_f32_16x16x32_bf16(qf[kc], kf, s2, 0,0,0);
  }
  bool valid = (c16 < 4);
  float m2[4], l2[4];
  #pragma unroll
  for (int r=0;r<4;r++) m2[r] = valid? s2[r] : -3e38f;
  #pragma unroll
  for (int m=1;m<16;m<<=1)
    #pragma unroll
    for (int r=0;r<4;r++) m2[r] = fmaxf(m2[r], __shfl_xor(m2[r], m));
  #pragma unroll
  for (int r=0;r<4;r++){ float p = valid? fexp2(s2[r]-m2[r]) : 0.f; s2[r]=p; l2[r]=p; }
  #pragma unroll
  for (int m=1;m<16;m<<=1)
    #pragma unroll
    for (int r=0;r<4;r++) l2[r] += __shfl_xor(l2[r], m);
  #pragma unroll
  for (int r=0;r<4;r++){
    int prow = w*16 + g*4 + r;
    int s0 = (c16>>3) ^ (prow&7);
    int s1 = (2 + (c16>>3)) ^ (prow&7);
    pwb[prow*64 + s0*8 + c7] = f2b(s2[r]);
    pwb[prow*64 + s1*8 + c7] = (u16)0;
  }
  int prow2 = w*16 + c16;
  s16x8 pf2 = *(const s16x8*)&pwb[prow2*64 + (g ^ c7)*8];
  f32x4 a2[8];
  #pragma unroll
  for (int dt=0;dt<8;dt++) a2[dt] = f32x4{0.f,0.f,0.f,0.f};
  #pragma unroll
  for (int dt=0;dt<8;dt++){
    int vrow = dt*16 + c16;
    s16x8 vf = *(const s16x8*)&vts[0][vrow*64 + (g ^ c7)*8];
    a2[dt] = __builtin_amdgcn_mfma_f32_16x16x32_bf16(pf2, vf, a2[dt], 0,0,0);
  }
  float sb = bscale[0];
  float rl[4], rl2[4];
  #pragma unroll
  for (int r=0;r<4;r++){ rl[r] = 1.f/l_[r]; rl2[r] = sb/l2[r]; }
  #pragma unroll
  for (int dt=0;dt<8;dt++)
    #pragma unroll
    for (int r=0;r<4;r++){
      int tok = qb + w*16 + g*4 + r;
      int col = h*HDM + dt*16 + c16;
      hs[(size_t)tok*DM + col] = f2b(acc[dt][r]*rl[r] + a2[dt][r]*rl2[r]);
    }
}

extern "C" void kernel_launch(void* const* d_in, const int* in_sizes, int n_in,
                              void* d_out, int out_size, void* d_ws, size_t ws_size,
                              hipStream_t stream){
  static const int expect[28] = {
    6291456, 1572864, 4096, 327680, 327680,
    9437184, 3072, 9437184, 3072, 9437184, 3072, 128, 128,
    9437184, 3072, 9437184, 3072, 9437184, 3072, 128, 128,
    9437184, 3072, 9437184, 3072, 3145728, 3145728, 1 };
  bool ok = (n_in == 28);
  if (ok) for (int i=0;i<28;i++) if (in_sizes[i] != expect[i]) { ok = false; break; }
  if (!ok){ fillv<<<(out_size+255)/256,256,0,stream>>>((float*)d_out, out_size, 7.0f); return; }
  if (ws_size < 119611392ull){ fillv<<<(out_size+255)/256,256,0,stream>>>((float*)d_out, out_size, 9.0f); return; }

  const float* hidden = (const float*)d_in[0];
  const float* enc    = (const float*)d_in[1];
  const float* adapt  = (const float*)d_in[2];
  const float* fcos   = (const float*)d_in[3];
  const float* fsin   = (const float*)d_in[4];
  const float* Wq  = (const float*)d_in[5];  const float* bq  = (const float*)d_in[6];
  const float* Wk  = (const float*)d_in[7];  const float* bk  = (const float*)d_in[8];
  const float* Wv  = (const float*)d_in[9];  const float* bv  = (const float*)d_in[10];
  const float* nqw = (const float*)d_in[11]; const float* nkw = (const float*)d_in[12];
  const float* Wqa = (const float*)d_in[13]; const float* bqa = (const float*)d_in[14];
  const float* Wka = (const float*)d_in[15]; const float* bka = (const float*)d_in[16];
  const float* Wva = (const float*)d_in[17]; const float* bva = (const float*)d_in[18];
  const float* naq = (const float*)d_in[19]; const float* nak = (const float*)d_in[20];
  const float* Wo  = (const float*)d_in[21]; const float* bo  = (const float*)d_in[22];
  const float* Woa = (const float*)d_in[23]; const float* boa = (const float*)d_in[24];
  const float* Wkad = (const float*)d_in[25]; const float* Wvad = (const float*)d_in[26];
  const float* bsc  = (const float*)d_in[27];
  float* out = (float*)d_out;

  char* ws = (char*)d_ws;
  u16* wt3   = (u16*)(ws);
  u16* kh    = (u16*)(ws);
  u16* vth   = (u16*)(ws + 15728640);
  u16* vdk   = (u16*)(ws + 31457280);
  u16* vdv   = (u16*)(ws + 31481856);
  u16* woaT  = (u16*)(ws + 33554432);
  u16* hbf   = (u16*)(ws + 56623104);
  u16* qh    = (u16*)(ws + 56623104);
  u16* qkvI  = (u16*)(ws + 72351744);
  u16* hsb   = (u16*)(ws + 72351744);
  u16* woT   = (u16*)(ws + 88080384);
  u16* qkvT  = (u16*)(ws + 110100480);
  float* biasA = (float*)(ws + 119537664);
  float* biasB = (float*)(ws + 119574528);

  castbias<<<3912,256,0,stream>>>(hidden, enc, hbf, 786432, 983040,
                                  bq,bk,bv, bqa,bka,bva, biasA);
  ktrans3<<<dim3(48,48,3),256,0,stream>>>(Wq, Wk, Wv, wt3, wt3 + (size_t)DM*DM, wt3 + (size_t)2*DM*DM);
  qkv_gemm<<<dim3(16,72),256,0,stream>>>(hbf, wt3, biasA, qkvI);
  ktrans3<<<dim3(48,48,3),256,0,stream>>>(Wqa, Wka, Wva, wt3, wt3 + (size_t)DM*DM, wt3 + (size_t)2*DM*DM);
  qkv_gemm<<<dim3(4,72),256,0,stream>>>(hbf + (size_t)2048*DM, wt3, biasB, qkvT);
  epi_fused<<<16416,256,0,stream>>>(qkvI, qkvT, nqw,nkw,naq,nak, fcos,fsin, qh, kh, vth,
                                    adapt, Wkad, Wvad, vdk, vdv);
  attnk<<<dim3(20,24),512,0,stream>>>(qh, kh, vth, vdk, vdv, bsc, hsb);
  ktrans3<<<dim3(48,48,2),256,0,stream>>>(Wo, Woa, Woa, woT, woaT, woaT);
  out_gemm<<<dim3(20,24),256,0,stream>>>(hsb, woT, woaT, bo, boa, out);
}

// Round 22
// 662.369 us; speedup vs baseline: 1.0741x; 1.0064x over previous
//
#include <hip/hip_runtime.h>

typedef unsigned short u16;
typedef short s16x8 __attribute__((ext_vector_type(8)));
typedef float f32x4 __attribute__((ext_vector_type(4)));

#define S_TXTC 512
#define S_TOTC 2560
#define DM 3072
#define NH 24
#define HDM 128

__device__ __forceinline__ float b2f(u16 u){ unsigned int i = ((unsigned int)u)<<16; float f; __builtin_memcpy(&f,&i,4); return f; }
__device__ __forceinline__ u16 f2b(float f){ unsigned int i; __builtin_memcpy(&i,&f,4); unsigned int r = i + 0x7FFFu + ((i>>16)&1u); return (u16)(r>>16); }
__device__ __forceinline__ unsigned int pk2(float lo, float hi){
  return (unsigned int)f2b(lo) | ((unsigned int)f2b(hi)<<16);
}
__device__ __forceinline__ s16x8 pk8(float4 a, float4 b){
  s16x8 r;
  r[0]=(short)f2b(a.x); r[1]=(short)f2b(a.y); r[2]=(short)f2b(a.z); r[3]=(short)f2b(a.w);
  r[4]=(short)f2b(b.x); r[5]=(short)f2b(b.y); r[6]=(short)f2b(b.z); r[7]=(short)f2b(b.w);
  return r;
}
__device__ __forceinline__ void g2l16(const void* g, void* l){
  __builtin_amdgcn_global_load_lds((const __attribute__((address_space(1))) void*)g,
                                   (__attribute__((address_space(3))) void*)l, 16, 0, 0);
}
__device__ __forceinline__ float fexp2(float x){ return __builtin_amdgcn_exp2f(x); }  // native v_exp_f32 (2^x)

__global__ __launch_bounds__(256) void fillv(float* __restrict__ p, int n, float v){
  int i = blockIdx.x*256 + threadIdx.x;
  if (i < n) p[i] = v;
}

// ---------------- cast hidden+enc fp32 -> bf16 + concat biases (merged) ----------------
__global__ __launch_bounds__(256) void castbias(const float* __restrict__ a, const float* __restrict__ b,
    u16* __restrict__ dst, int na8, int n8,
    const float* __restrict__ b0, const float* __restrict__ b1, const float* __restrict__ b2,
    const float* __restrict__ c0, const float* __restrict__ c1, const float* __restrict__ c2,
    float* __restrict__ bdst){
  int blk = blockIdx.x;
  if (blk < 3840){
    int i = blk*256 + threadIdx.x;
    if (i >= n8) return;
    const float* src = (i < na8)? a + (size_t)i*8 : b + (size_t)(i-na8)*8;
    float4 f0 = *(const float4*)src;
    float4 f1 = *(const float4*)(src+4);
    *(s16x8*)(dst + (size_t)i*8) = pk8(f0,f1);
  } else {
    int i = (blk-3840)*256 + threadIdx.x;
    if (i >= 18432) return;
    int j = (i < 9216)? i : i - 9216;
    const float* s0 = (i<9216)? b0 : c0; const float* s1 = (i<9216)? b1 : c1; const float* s2 = (i<9216)? b2 : c2;
    bdst[i] = (j<3072)? s0[j] : (j<6144? s1[j-3072] : s2[j-6144]);
  }
}

__global__ __launch_bounds__(256) void ktrans3(const float* __restrict__ W0, const float* __restrict__ W1,
    const float* __restrict__ W2, u16* __restrict__ D0, u16* __restrict__ D1, u16* __restrict__ D2){
  const float* W = (blockIdx.z==0)? W0 : ((blockIdx.z==1)? W1 : W2);
  u16* Wt = (blockIdx.z==0)? D0 : ((blockIdx.z==1)? D1 : D2);
  __shared__ __align__(16) u16 t[64*72];
  int nt = blockIdx.x*64, kt_ = blockIdx.y*64;
  int tid = threadIdx.x;
  #pragma unroll
  for (int i=0;i<2;i++){
    int q = tid + 256*i;
    int r = q>>3, c8 = (q&7)*8;
    float4 f0 = *(const float4*)(W + (size_t)(kt_+r)*DM + nt + c8);
    float4 f1 = *(const float4*)(W + (size_t)(kt_+r)*DM + nt + c8 + 4);
    *(s16x8*)&t[r*72 + c8] = pk8(f0,f1);
  }
  __syncthreads();
  #pragma unroll
  for (int i=0;i<2;i++){
    int q = tid + 256*i;
    int n = q>>3, k8 = (q&7)*8;
    s16x8 v;
    #pragma unroll
    for (int j=0;j<8;j++) v[j] = (short)t[(k8+j)*72 + n];
    *(s16x8*)(Wt + (size_t)(nt+n)*DM + kt_ + k8) = v;
  }
}

// ---------------- m97-style bf16 GEMM core ----------------
template<int OUT32>
__device__ __forceinline__ void gcore(u16* la, u16* lb,
    const u16* __restrict__ A, const u16* __restrict__ Bt,
    const float* __restrict__ bias, void* __restrict__ Cv,
    int ldc, int rb, int crb, int cb){
  const int K = DM;
  int tid = threadIdx.x, w = tid>>6, l = tid&63, g = l>>4, c16 = l&15;
  int wr = (w>>1)*64, wc = (w&1)*64;
  f32x4 acc[4][4] = {};
  const u16* aL = A  + (size_t)(rb + w*32 + (l>>2))*K + (l&3)*8;
  const u16* bL = Bt + (size_t)(cb + w*32 + (l>>2))*K + (l&3)*8;
  u16* laB = la + w*1024;
  u16* lbB = lb + w*1024;
  for (int ks=0; ks<K; ks+=32){
    g2l16(aL + ks,                laB);
    g2l16(aL + 16*(size_t)K + ks, laB + 512);
    g2l16(bL + ks,                lbB);
    g2l16(bL + 16*(size_t)K + ks, lbB + 512);
    __syncthreads();
    s16x8 af[4], bf[4];
    #pragma unroll
    for (int m=0;m<4;m++) af[m] = *(const s16x8*)&la[(wr + m*16 + c16)*32 + g*8];
    #pragma unroll
    for (int n=0;n<4;n++) bf[n] = *(const s16x8*)&lb[(wc + n*16 + c16)*32 + g*8];
    #pragma unroll
    for (int m=0;m<4;m++)
      #pragma unroll
      for (int n=0;n<4;n++)
        acc[m][n] = __builtin_amdgcn_mfma_f32_16x16x32_bf16(af[m], bf[n], acc[m][n], 0,0,0);
    __syncthreads();
  }
  #pragma unroll
  for (int n=0;n<4;n++){
    int col = cb + wc + n*16 + c16;
    float bv = bias[col];
    #pragma unroll
    for (int m=0;m<4;m++){
      int r0 = crb + wr + m*16 + g*4;
      #pragma unroll
      for (int r=0;r<4;r++){
        float oo = acc[m][n][r] + bv;
        if (OUT32) ((float*)Cv)[(size_t)(r0+r)*ldc + col] = oo;
        else       ((u16*)Cv)[(size_t)(r0+r)*ldc + col] = f2b(oo);
      }
    }
  }
}

// XCD-chunked bijective block swizzle (requires nwg % 8 == 0)
__device__ __forceinline__ void xcd_swz(int& bx, int& by){
  int gx = gridDim.x, nwg = gx*gridDim.y;
  int id = blockIdx.y*gx + blockIdx.x;
  int q = nwg>>3;
  int nid = (id&7)*q + (id>>3);
  bx = nid % gx; by = nid / gx;
}

__global__ __launch_bounds__(256) void qkv_gemm(const u16* __restrict__ A, const u16* __restrict__ Bt,
                                                const float* __restrict__ bias, u16* __restrict__ C){
  __shared__ __align__(16) u16 la[4096];
  __shared__ __align__(16) u16 lb[4096];
  int bx, by; xcd_swz(bx, by);
  gcore<0>(la, lb, A, Bt, bias, C, 3*DM, bx*128, bx*128, by*128);
}

__global__ __launch_bounds__(256) void out_gemm(const u16* __restrict__ hsb,
    const u16* __restrict__ woT, const u16* __restrict__ woaT,
    const float* __restrict__ bo, const float* __restrict__ boa, float* __restrict__ out){
  __shared__ __align__(16) u16 la[4096];
  __shared__ __align__(16) u16 lb[4096];
  int bx, by; xcd_swz(bx, by);
  bool txt = (bx < 4);
  int rb = bx*128;
  const u16* Bt = txt? woaT : woT;
  const float* bias = txt? boa : bo;
  float* dst = txt? out + (size_t)2048*DM : out;
  int crb = txt? rb : rb - 512;
  gcore<1>(la, lb, hsb, Bt, bias, dst, DM, rb, crb, by*128);
}

// ---------------- fused epilogues + adapter projections ----------------
// blocks [0,15360): qk RMSNorm+RoPE (2 rows/wave); [15360,16320): v transpose; [16320,16416): adapter GEMV
__global__ __launch_bounds__(256) void epi_fused(
    const u16* __restrict__ qkvI, const u16* __restrict__ qkvT,
    const float* __restrict__ nqw, const float* __restrict__ nkw,
    const float* __restrict__ naq, const float* __restrict__ nak,
    const float* __restrict__ fcos, const float* __restrict__ fsin,
    u16* __restrict__ qh, u16* __restrict__ kh, u16* __restrict__ vt,
    const float* __restrict__ ad, const float* __restrict__ Wkad, const float* __restrict__ Wvad,
    u16* __restrict__ vdk, u16* __restrict__ vdv){
  __shared__ __align__(16) u16 t[64*136];
  int blk = blockIdx.x;
  if (blk < 15360){
    int lane = threadIdx.x&63;
    int rowid = blk*8 + (threadIdx.x>>6)*2 + (lane>>5);
    int which = rowid / (NH*S_TOTC);
    int rem = rowid % (NH*S_TOTC);
    int h = rem / S_TOTC, tok = rem % S_TOTC;
    const u16* src = ((tok<S_TXTC)? qkvT + (size_t)tok*(3*DM) : qkvI + (size_t)(tok-S_TXTC)*(3*DM))
                     + which*DM + h*HDM;
    const float* nw = which? ((tok<S_TXTC)? nak : nkw) : ((tok<S_TXTC)? naq : nqw);
    int d = (lane&31)*4;
    uint2 u = *(const uint2*)(src + d);
    float x0 = b2f((u16)(u.x&0xffffu)), x1 = b2f((u16)(u.x>>16));
    float x2 = b2f((u16)(u.y&0xffffu)), x3 = b2f((u16)(u.y>>16));
    float ss = x0*x0 + x1*x1 + x2*x2 + x3*x3;
    #pragma unroll
    for (int m=1;m<32;m<<=1) ss += __shfl_xor(ss, m);
    float rr = rsqrtf(ss*(1.f/128.f) + 1e-6f);
    float4 nv = *(const float4*)(nw + d);
    float y0 = x0*rr*nv.x, y1 = x1*rr*nv.y, y2 = x2*rr*nv.z, y3 = x3*rr*nv.w;
    float4 cc = *(const float4*)(fcos + (size_t)tok*HDM + d);
    float4 sn = *(const float4*)(fsin + (size_t)tok*HDM + d);
    // Q: fold 1/sqrt(HD) * log2(e) so attn softmax runs in exp2 domain
    float sc = which? 1.0f : 0.1275174436f;
    float o0 = (y0*cc.x - y1*sn.x)*sc;
    float o1 = (y1*cc.y + y0*sn.y)*sc;
    float o2 = (y2*cc.z - y3*sn.z)*sc;
    float o3 = (y3*cc.w + y2*sn.w)*sc;
    u16* dst = (which? kh : qh) + ((size_t)h*S_TOTC + tok)*HDM + d;
    uint2 ov; ov.x = pk2(o0,o1); ov.y = pk2(o2,o3);
    *(uint2*)dst = ov;
  } else if (blk < 16320){
    int bv = blk - 15360;
    int h = bv % NH, tb = bv / NH;
    int tok0 = tb*64, tid = threadIdx.x;
    #pragma unroll
    for (int i=0;i<4;i++){
      int q = tid + 256*i;
      int tr = q>>4, c8 = (q&15)*8;
      int tok = tok0 + tr;
      const u16* src = ((tok<S_TXTC)? qkvT + (size_t)tok*(3*DM) : qkvI + (size_t)(tok-S_TXTC)*(3*DM))
                       + 2*DM + h*HDM;
      *(s16x8*)&t[tr*136 + c8] = *(const s16x8*)(src + c8);
    }
    __syncthreads();
    #pragma unroll
    for (int i=0;i<4;i++){
      int q = tid + 256*i;
      int d = q>>3, j8 = (q&7)*8;
      s16x8 v;
      #pragma unroll
      for (int j=0;j<8;j++) v[j] = (short)t[(j8+j)*136 + d];
      *(s16x8*)(vt + ((size_t)h*HDM + d)*S_TOTC + tok0 + j8) = v;
    }
  } else {
    // adapter: 96 blocks = 2 tensors x 48 col-strips of 64; lanes sweep W rows (coalesced)
    int bv = blk - 16320;
    int tensor = bv / 48;
    int col = (bv % 48)*64 + (threadIdx.x & 63);
    int tok = threadIdx.x >> 6;
    const float* Wp = tensor? Wvad : Wkad;
    const float* arow = ad + tok*1024;
    float s = 0.f;
    #pragma unroll 4
    for (int k=0;k<1024;k++)
      s += arow[k] * Wp[(size_t)k*DM + col];
    int hh = col>>7, d = col&127;
    (tensor? vdv : vdk)[(hh*4+tok)*HDM + d] = f2b(s);
  }
}

// ---------------- attn: QBLK=128, 8 waves, KVBLK=64, g2l16 dbuf, native-exp2 softmax, setprio ----------------
__global__ __launch_bounds__(512,2) void attnk(const u16* __restrict__ qh, const u16* __restrict__ kh,
    const u16* __restrict__ vt, const u16* __restrict__ vdk, const u16* __restrict__ vdv,
    const float* __restrict__ bscale, u16* __restrict__ hs){
  __shared__ __align__(16) u16 kts[2][64*128];   // [key][d], slot ^= row&7 (via pre-swizzled source)
  __shared__ __align__(16) u16 vts[2][128*64];   // [d][key], slot ^= row&7
  __shared__ __align__(16) u16 pwb[128*64];      // [q][key], slot ^= row&7 (wave-private rows)
  int h = blockIdx.y, qb = blockIdx.x*128;
  int tid = threadIdx.x, w = tid>>6, l = tid&63, g = l>>4, c16 = l&15;
  int qrow = qb + w*16 + c16;
  int c7 = c16&7;
  s16x8 qf[4];
  #pragma unroll
  for (int kc=0;kc<4;kc++) qf[kc] = *(const s16x8*)(qh + ((size_t)h*S_TOTC + qrow)*HDM + kc*32 + g*8);
  f32x4 acc[8];
  #pragma unroll
  for (int dt=0;dt<8;dt++) acc[dt] = f32x4{0.f,0.f,0.f,0.f};
  float m_[4] = {-3e38f,-3e38f,-3e38f,-3e38f};
  float l_[4] = {0.f,0.f,0.f,0.f};
  const u16* khB = kh + (size_t)h*S_TOTC*HDM;
  const u16* vtB = vt + (size_t)h*HDM*S_TOTC;

  auto STAGE = [&](int buf, int kb){
    #pragma unroll
    for (int c=0;c<2;c++){
      int krow = w*8 + c*4 + (l>>4);
      int kchunk = (l&15) ^ (krow&7);
      g2l16(khB + (size_t)(kb + krow)*HDM + kchunk*8, &kts[buf][w*1024 + c*512]);
      int vrow = w*16 + c*8 + (l>>3);
      int vchunk = (l&7) ^ (vrow&7);
      g2l16(vtB + (size_t)vrow*S_TOTC + kb + vchunk*8, &vts[buf][w*1024 + c*512]);
    }
  };
  auto COMPUTE = [&](int buf){
    f32x4 s[4];
    #pragma unroll
    for (int su=0;su<4;su++) s[su] = f32x4{0.f,0.f,0.f,0.f};
    __builtin_amdgcn_s_setprio(1);
    #pragma unroll
    for (int su=0;su<4;su++)
      #pragma unroll
      for (int kc=0;kc<4;kc++){
        s16x8 kf = *(const s16x8*)&kts[buf][(su*16+c16)*128 + ((kc*4+g) ^ c7)*8];
        s[su] = __builtin_amdgcn_mfma_f32_16x16x32_bf16(qf[kc], kf, s[su], 0,0,0);
      }
    __builtin_amdgcn_s_setprio(0);
    float tm[4];
    #pragma unroll
    for (int r=0;r<4;r++)
      tm[r] = fmaxf(fmaxf(s[0][r],s[1][r]), fmaxf(s[2][r],s[3][r]));
    #pragma unroll
    for (int m=1;m<16;m<<=1)
      #pragma unroll
      for (int r=0;r<4;r++) tm[r] = fmaxf(tm[r], __shfl_xor(tm[r], m));
    bool need = !__all(tm[0]<=m_[0]+11.5415603f && tm[1]<=m_[1]+11.5415603f &&
                       tm[2]<=m_[2]+11.5415603f && tm[3]<=m_[3]+11.5415603f);
    if (need){
      float corr[4];
      #pragma unroll
      for (int r=0;r<4;r++){
        float mn = fmaxf(m_[r], tm[r]);
        corr[r] = fexp2(m_[r]-mn);
        m_[r] = mn;
        l_[r] *= corr[r];
      }
      #pragma unroll
      for (int dt=0;dt<8;dt++)
        #pragma unroll
        for (int r=0;r<4;r++) acc[dt][r] *= corr[r];
    }
    float rs[4];
    #pragma unroll
    for (int r=0;r<4;r++){
      rs[r] = 0.f;
      #pragma unroll
      for (int su=0;su<4;su++){ s[su][r] = fexp2(s[su][r]-m_[r]); rs[r] += s[su][r]; }
    }
    #pragma unroll
    for (int m=1;m<16;m<<=1)
      #pragma unroll
      for (int r=0;r<4;r++) rs[r] += __shfl_xor(rs[r], m);
    #pragma unroll
    for (int r=0;r<4;r++) l_[r] += rs[r];
    #pragma unroll
    for (int su=0;su<4;su++){
      int kslot = su*2 + (c16>>3);
      #pragma unroll
      for (int r=0;r<4;r++){
        int prow = w*16 + g*4 + r;
        pwb[prow*64 + (kslot ^ (prow&7))*8 + c7] = f2b(s[su][r]);
      }
    }
    int prow = w*16 + c16;
    s16x8 pf0 = *(const s16x8*)&pwb[prow*64 + ((0+g) ^ c7)*8];
    s16x8 pf1 = *(const s16x8*)&pwb[prow*64 + ((4+g) ^ c7)*8];
    __builtin_amdgcn_s_setprio(1);
    #pragma unroll
    for (int dt=0;dt<8;dt++){
      int vrow = dt*16 + c16;
      s16x8 vf0 = *(const s16x8*)&vts[buf][vrow*64 + ((0+g) ^ c7)*8];
      acc[dt] = __builtin_amdgcn_mfma_f32_16x16x32_bf16(pf0, vf0, acc[dt], 0,0,0);
      s16x8 vf1 = *(const s16x8*)&vts[buf][vrow*64 + ((4+g) ^ c7)*8];
      acc[dt] = __builtin_amdgcn_mfma_f32_16x16x32_bf16(pf1, vf1, acc[dt], 0,0,0);
    }
    __builtin_amdgcn_s_setprio(0);
  };

  STAGE(0, 0);
  __syncthreads();
  int cur = 0;
  for (int kb=0; kb<S_TOTC; kb+=64){
    if (kb+64 < S_TOTC) STAGE(cur^1, kb+64);
    COMPUTE(cur);
    __syncthreads();
    cur ^= 1;
  }

  // adapter cross-attention tile (4 valid keys), native exp2, stale rows masked by P=0
  if (tid < 64){
    int row = tid>>4, slot = (tid&15) ^ (row&7);
    *(s16x8*)&kts[0][row*128 + slot*8] = *(const s16x8*)(vdk + (h*4+(tid>>4))*HDM + (tid&15)*8);
  } else if (tid < 192){
    int d = tid - 64;
    int sl0 = (d&7)*8;
    #pragma unroll
    for (int key=0;key<4;key++) vts[0][d*64 + sl0 + key] = vdv[(h*4+key)*HDM + d];
  }
  __syncthreads();
  f32x4 s2 = {0.f,0.f,0.f,0.f};
  #pragma unroll
  for (int kc=0;kc<4;kc++){
    s16x8 kf = *(const s16x8*)&kts[0][c16*128 + ((kc*4+g) ^ c7)*8];
    s2 = __builtin_amdgcn_mfma_f32_16x16x32_bf16(qf[kc], kf, s2, 0,0,0);
  }
  bool valid = (c16 < 4);
  float m2[4], l2[4];
  #pragma unroll
  for (int r=0;r<4;r++) m2[r] = valid? s2[r] : -3e38f;
  #pragma unroll
  for (int m=1;m<16;m<<=1)
    #pragma unroll
    for (int r=0;r<4;r++) m2[r] = fmaxf(m2[r], __shfl_xor(m2[r], m));
  #pragma unroll
  for (int r=0;r<4;r++){ float p = valid? fexp2(s2[r]-m2[r]) : 0.f; s2[r]=p; l2[r]=p; }
  #pragma unroll
  for (int m=1;m<16;m<<=1)
    #pragma unroll
    for (int r=0;r<4;r++) l2[r] += __shfl_xor(l2[r], m);
  #pragma unroll
  for (int r=0;r<4;r++){
    int prow = w*16 + g*4 + r;
    int s0 = (c16>>3) ^ (prow&7);
    int s1 = (2 + (c16>>3)) ^ (prow&7);
    pwb[prow*64 + s0*8 + c7] = f2b(s2[r]);
    pwb[prow*64 + s1*8 + c7] = (u16)0;
  }
  int prow2 = w*16 + c16;
  s16x8 pf2 = *(const s16x8*)&pwb[prow2*64 + (g ^ c7)*8];
  f32x4 a2[8];
  #pragma unroll
  for (int dt=0;dt<8;dt++) a2[dt] = f32x4{0.f,0.f,0.f,0.f};
  #pragma unroll
  for (int dt=0;dt<8;dt++){
    int vrow = dt*16 + c16;
    s16x8 vf = *(const s16x8*)&vts[0][vrow*64 + (g ^ c7)*8];
    a2[dt] = __builtin_amdgcn_mfma_f32_16x16x32_bf16(pf2, vf, a2[dt], 0,0,0);
  }
  float sb = bscale[0];
  float rl[4], rl2[4];
  #pragma unroll
  for (int r=0;r<4;r++){ rl[r] = 1.f/l_[r]; rl2[r] = sb/l2[r]; }
  #pragma unroll
  for (int dt=0;dt<8;dt++)
    #pragma unroll
    for (int r=0;r<4;r++){
      int tok = qb + w*16 + g*4 + r;
      int col = h*HDM + dt*16 + c16;
      hs[(size_t)tok*DM + col] = f2b(acc[dt][r]*rl[r] + a2[dt][r]*rl2[r]);
    }
}

extern "C" void kernel_launch(void* const* d_in, const int* in_sizes, int n_in,
                              void* d_out, int out_size, void* d_ws, size_t ws_size,
                              hipStream_t stream){
  static const int expect[28] = {
    6291456, 1572864, 4096, 327680, 327680,
    9437184, 3072, 9437184, 3072, 9437184, 3072, 128, 128,
    9437184, 3072, 9437184, 3072, 9437184, 3072, 128, 128,
    9437184, 3072, 9437184, 3072, 3145728, 3145728, 1 };
  bool ok = (n_in == 28);
  if (ok) for (int i=0;i<28;i++) if (in_sizes[i] != expect[i]) { ok = false; break; }
  if (!ok){ fillv<<<(out_size+255)/256,256,0,stream>>>((float*)d_out, out_size, 7.0f); return; }
  if (ws_size < 119611392ull){ fillv<<<(out_size+255)/256,256,0,stream>>>((float*)d_out, out_size, 9.0f); return; }

  const float* hidden = (const float*)d_in[0];
  const float* enc    = (const float*)d_in[1];
  const float* adapt  = (const float*)d_in[2];
  const float* fcos   = (const float*)d_in[3];
  const float* fsin   = (const float*)d_in[4];
  const float* Wq  = (const float*)d_in[5];  const float* bq  = (const float*)d_in[6];
  const float* Wk  = (const float*)d_in[7];  const float* bk  = (const float*)d_in[8];
  const float* Wv  = (const float*)d_in[9];  const float* bv  = (const float*)d_in[10];
  const float* nqw = (const float*)d_in[11]; const float* nkw = (const float*)d_in[12];
  const float* Wqa = (const float*)d_in[13]; const float* bqa = (const float*)d_in[14];
  const float* Wka = (const float*)d_in[15]; const float* bka = (const float*)d_in[16];
  const float* Wva = (const float*)d_in[17]; const float* bva = (const float*)d_in[18];
  const float* naq = (const float*)d_in[19]; const float* nak = (const float*)d_in[20];
  const float* Wo  = (const float*)d_in[21]; const float* bo  = (const float*)d_in[22];
  const float* Woa = (const float*)d_in[23]; const float* boa = (const float*)d_in[24];
  const float* Wkad = (const float*)d_in[25]; const float* Wvad = (const float*)d_in[26];
  const float* bsc  = (const float*)d_in[27];
  float* out = (float*)d_out;

  char* ws = (char*)d_ws;
  u16* wt3   = (u16*)(ws);
  u16* kh    = (u16*)(ws);
  u16* vth   = (u16*)(ws + 15728640);
  u16* vdk   = (u16*)(ws + 31457280);
  u16* vdv   = (u16*)(ws + 31481856);
  u16* woaT  = (u16*)(ws + 33554432);
  u16* hbf   = (u16*)(ws + 56623104);
  u16* qh    = (u16*)(ws + 56623104);
  u16* qkvI  = (u16*)(ws + 72351744);
  u16* hsb   = (u16*)(ws + 72351744);
  u16* woT   = (u16*)(ws + 88080384);
  u16* qkvT  = (u16*)(ws + 110100480);
  float* biasA = (float*)(ws + 119537664);
  float* biasB = (float*)(ws + 119574528);

  castbias<<<3912,256,0,stream>>>(hidden, enc, hbf, 786432, 983040,
                                  bq,bk,bv, bqa,bka,bva, biasA);
  // img QKV: transpose Wq/Wk/Wv then GEMM
  ktrans3<<<dim3(48,48,3),256,0,stream>>>(Wq, Wk, Wv, wt3, wt3 + (size_t)DM*DM, wt3 + (size_t)2*DM*DM);
  qkv_gemm<<<dim3(16,72),256,0,stream>>>(hbf, wt3, biasA, qkvI);
  // txt QKV: transpose Wqa/Wka/Wva (REQUIRED - reuses wt3) then GEMM
  ktrans3<<<dim3(48,48,3),256,0,stream>>>(Wqa, Wka, Wva, wt3, wt3 + (size_t)DM*DM, wt3 + (size_t)2*DM*DM);
  qkv_gemm<<<dim3(4,72),256,0,stream>>>(hbf + (size_t)2048*DM, wt3, biasB, qkvT);
  epi_fused<<<16416,256,0,stream>>>(qkvI, qkvT, nqw,nkw,naq,nak, fcos,fsin, qh, kh, vth,
                                    adapt, Wkad, Wvad, vdk, vdv);
  attnk<<<dim3(20,24),512,0,stream>>>(qh, kh, vth, vdk, vdv, bsc, hsb);
  ktrans3<<<dim3(48,48,2),256,0,stream>>>(Wo, Woa, Woa, woT, woaT, woaT);
  out_gemm<<<dim3(20,24),256,0,stream>>>(hsb, woT, woaT, bo, boa, out);
}

// Round 23
// 660.857 us; speedup vs baseline: 1.0765x; 1.0023x over previous
//
#include <hip/hip_runtime.h>

typedef unsigned short u16;
typedef short s16x8 __attribute__((ext_vector_type(8)));
typedef float f32x4 __attribute__((ext_vector_type(4)));

#define S_TXTC 512
#define S_TOTC 2560
#define DM 3072
#define NH 24
#define HDM 128

__device__ __forceinline__ float b2f(u16 u){ unsigned int i = ((unsigned int)u)<<16; float f; __builtin_memcpy(&f,&i,4); return f; }
__device__ __forceinline__ u16 f2b(float f){ unsigned int i; __builtin_memcpy(&i,&f,4); unsigned int r = i + 0x7FFFu + ((i>>16)&1u); return (u16)(r>>16); }
__device__ __forceinline__ unsigned int pk2(float lo, float hi){
  return (unsigned int)f2b(lo) | ((unsigned int)f2b(hi)<<16);
}
__device__ __forceinline__ s16x8 pk8(float4 a, float4 b){
  s16x8 r;
  r[0]=(short)f2b(a.x); r[1]=(short)f2b(a.y); r[2]=(short)f2b(a.z); r[3]=(short)f2b(a.w);
  r[4]=(short)f2b(b.x); r[5]=(short)f2b(b.y); r[6]=(short)f2b(b.z); r[7]=(short)f2b(b.w);
  return r;
}
__device__ __forceinline__ void g2l16(const void* g, void* l){
  __builtin_amdgcn_global_load_lds((const __attribute__((address_space(1))) void*)g,
                                   (__attribute__((address_space(3))) void*)l, 16, 0, 0);
}
__device__ __forceinline__ float fexp2(float x){ return __builtin_amdgcn_exp2f(x); }  // native v_exp_f32 (2^x)

__global__ __launch_bounds__(256) void fillv(float* __restrict__ p, int n, float v){
  int i = blockIdx.x*256 + threadIdx.x;
  if (i < n) p[i] = v;
}

// ---------------- cast hidden+enc fp32 -> bf16 + concat biases (merged) ----------------
__global__ __launch_bounds__(256) void castbias(const float* __restrict__ a, const float* __restrict__ b,
    u16* __restrict__ dst, int na8, int n8,
    const float* __restrict__ b0, const float* __restrict__ b1, const float* __restrict__ b2,
    const float* __restrict__ c0, const float* __restrict__ c1, const float* __restrict__ c2,
    float* __restrict__ bdst){
  int blk = blockIdx.x;
  if (blk < 3840){
    int i = blk*256 + threadIdx.x;
    if (i >= n8) return;
    const float* src = (i < na8)? a + (size_t)i*8 : b + (size_t)(i-na8)*8;
    float4 f0 = *(const float4*)src;
    float4 f1 = *(const float4*)(src+4);
    *(s16x8*)(dst + (size_t)i*8) = pk8(f0,f1);
  } else {
    int i = (blk-3840)*256 + threadIdx.x;
    if (i >= 18432) return;
    int j = (i < 9216)? i : i - 9216;
    const float* s0 = (i<9216)? b0 : c0; const float* s1 = (i<9216)? b1 : c1; const float* s2 = (i<9216)? b2 : c2;
    bdst[i] = (j<3072)? s0[j] : (j<6144? s1[j-3072] : s2[j-6144]);
  }
}

__global__ __launch_bounds__(256) void ktrans3(const float* __restrict__ W0, const float* __restrict__ W1,
    const float* __restrict__ W2, u16* __restrict__ D0, u16* __restrict__ D1, u16* __restrict__ D2){
  const float* W = (blockIdx.z==0)? W0 : ((blockIdx.z==1)? W1 : W2);
  u16* Wt = (blockIdx.z==0)? D0 : ((blockIdx.z==1)? D1 : D2);
  __shared__ __align__(16) u16 t[64*72];
  int nt = blockIdx.x*64, kt_ = blockIdx.y*64;
  int tid = threadIdx.x;
  #pragma unroll
  for (int i=0;i<2;i++){
    int q = tid + 256*i;
    int r = q>>3, c8 = (q&7)*8;
    float4 f0 = *(const float4*)(W + (size_t)(kt_+r)*DM + nt + c8);
    float4 f1 = *(const float4*)(W + (size_t)(kt_+r)*DM + nt + c8 + 4);
    *(s16x8*)&t[r*72 + c8] = pk8(f0,f1);
  }
  __syncthreads();
  #pragma unroll
  for (int i=0;i<2;i++){
    int q = tid + 256*i;
    int n = q>>3, k8 = (q&7)*8;
    s16x8 v;
    #pragma unroll
    for (int j=0;j<8;j++) v[j] = (short)t[(k8+j)*72 + n];
    *(s16x8*)(Wt + (size_t)(nt+n)*DM + kt_ + k8) = v;
  }
}

// ---------------- m97-style bf16 GEMM core ----------------
template<int OUT32>
__device__ __forceinline__ void gcore(u16* la, u16* lb,
    const u16* __restrict__ A, const u16* __restrict__ Bt,
    const float* __restrict__ bias, void* __restrict__ Cv,
    int ldc, int rb, int crb, int cb){
  const int K = DM;
  int tid = threadIdx.x, w = tid>>6, l = tid&63, g = l>>4, c16 = l&15;
  int wr = (w>>1)*64, wc = (w&1)*64;
  f32x4 acc[4][4] = {};
  const u16* aL = A  + (size_t)(rb + w*32 + (l>>2))*K + (l&3)*8;
  const u16* bL = Bt + (size_t)(cb + w*32 + (l>>2))*K + (l&3)*8;
  u16* laB = la + w*1024;
  u16* lbB = lb + w*1024;
  for (int ks=0; ks<K; ks+=32){
    g2l16(aL + ks,                laB);
    g2l16(aL + 16*(size_t)K + ks, laB + 512);
    g2l16(bL + ks,                lbB);
    g2l16(bL + 16*(size_t)K + ks, lbB + 512);
    __syncthreads();
    s16x8 af[4], bf[4];
    #pragma unroll
    for (int m=0;m<4;m++) af[m] = *(const s16x8*)&la[(wr + m*16 + c16)*32 + g*8];
    #pragma unroll
    for (int n=0;n<4;n++) bf[n] = *(const s16x8*)&lb[(wc + n*16 + c16)*32 + g*8];
    #pragma unroll
    for (int m=0;m<4;m++)
      #pragma unroll
      for (int n=0;n<4;n++)
        acc[m][n] = __builtin_amdgcn_mfma_f32_16x16x32_bf16(af[m], bf[n], acc[m][n], 0,0,0);
    __syncthreads();
  }
  #pragma unroll
  for (int n=0;n<4;n++){
    int col = cb + wc + n*16 + c16;
    float bv = bias[col];
    #pragma unroll
    for (int m=0;m<4;m++){
      int r0 = crb + wr + m*16 + g*4;
      #pragma unroll
      for (int r=0;r<4;r++){
        float oo = acc[m][n][r] + bv;
        if (OUT32) ((float*)Cv)[(size_t)(r0+r)*ldc + col] = oo;
        else       ((u16*)Cv)[(size_t)(r0+r)*ldc + col] = f2b(oo);
      }
    }
  }
}

// XCD-chunked bijective block swizzle (requires nwg % 8 == 0)
__device__ __forceinline__ void xcd_swz(int& bx, int& by){
  int gx = gridDim.x, nwg = gx*gridDim.y;
  int id = blockIdx.y*gx + blockIdx.x;
  int q = nwg>>3;
  int nid = (id&7)*q + (id>>3);
  bx = nid % gx; by = nid / gx;
}

__global__ __launch_bounds__(256) void qkv_gemm(const u16* __restrict__ A, const u16* __restrict__ Bt,
                                                const float* __restrict__ bias, u16* __restrict__ C){
  __shared__ __align__(16) u16 la[4096];
  __shared__ __align__(16) u16 lb[4096];
  int bx, by; xcd_swz(bx, by);
  gcore<0>(la, lb, A, Bt, bias, C, 3*DM, bx*128, bx*128, by*128);
}

__global__ __launch_bounds__(256) void out_gemm(const u16* __restrict__ hsb,
    const u16* __restrict__ woT, const u16* __restrict__ woaT,
    const float* __restrict__ bo, const float* __restrict__ boa, float* __restrict__ out){
  __shared__ __align__(16) u16 la[4096];
  __shared__ __align__(16) u16 lb[4096];
  int bx, by; xcd_swz(bx, by);
  bool txt = (bx < 4);
  int rb = bx*128;
  const u16* Bt = txt? woaT : woT;
  const float* bias = txt? boa : bo;
  float* dst = txt? out + (size_t)2048*DM : out;
  int crb = txt? rb : rb - 512;
  gcore<1>(la, lb, hsb, Bt, bias, dst, DM, rb, crb, by*128);
}

// ---------------- fused epilogues + adapter projections ----------------
// blocks [0,15360): qk RMSNorm+RoPE (2 rows/wave); [15360,16320): v transpose; [16320,16416): adapter GEMV
__global__ __launch_bounds__(256) void epi_fused(
    const u16* __restrict__ qkvI, const u16* __restrict__ qkvT,
    const float* __restrict__ nqw, const float* __restrict__ nkw,
    const float* __restrict__ naq, const float* __restrict__ nak,
    const float* __restrict__ fcos, const float* __restrict__ fsin,
    u16* __restrict__ qh, u16* __restrict__ kh, u16* __restrict__ vt,
    const float* __restrict__ ad, const float* __restrict__ Wkad, const float* __restrict__ Wvad,
    u16* __restrict__ vdk, u16* __restrict__ vdv){
  __shared__ __align__(16) u16 t[64*136];
  int blk = blockIdx.x;
  if (blk < 15360){
    int lane = threadIdx.x&63;
    int rowid = blk*8 + (threadIdx.x>>6)*2 + (lane>>5);
    int which = rowid / (NH*S_TOTC);
    int rem = rowid % (NH*S_TOTC);
    int h = rem / S_TOTC, tok = rem % S_TOTC;
    const u16* src = ((tok<S_TXTC)? qkvT + (size_t)tok*(3*DM) : qkvI + (size_t)(tok-S_TXTC)*(3*DM))
                     + which*DM + h*HDM;
    const float* nw = which? ((tok<S_TXTC)? nak : nkw) : ((tok<S_TXTC)? naq : nqw);
    int d = (lane&31)*4;
    uint2 u = *(const uint2*)(src + d);
    float x0 = b2f((u16)(u.x&0xffffu)), x1 = b2f((u16)(u.x>>16));
    float x2 = b2f((u16)(u.y&0xffffu)), x3 = b2f((u16)(u.y>>16));
    float ss = x0*x0 + x1*x1 + x2*x2 + x3*x3;
    #pragma unroll
    for (int m=1;m<32;m<<=1) ss += __shfl_xor(ss, m);
    float rr = rsqrtf(ss*(1.f/128.f) + 1e-6f);
    float4 nv = *(const float4*)(nw + d);
    float y0 = x0*rr*nv.x, y1 = x1*rr*nv.y, y2 = x2*rr*nv.z, y3 = x3*rr*nv.w;
    float4 cc = *(const float4*)(fcos + (size_t)tok*HDM + d);
    float4 sn = *(const float4*)(fsin + (size_t)tok*HDM + d);
    // Q: fold 1/sqrt(HD) * log2(e) so attn softmax runs in exp2 domain
    float sc = which? 1.0f : 0.1275174436f;
    float o0 = (y0*cc.x - y1*sn.x)*sc;
    float o1 = (y1*cc.y + y0*sn.y)*sc;
    float o2 = (y2*cc.z - y3*sn.z)*sc;
    float o3 = (y3*cc.w + y2*sn.w)*sc;
    u16* dst = (which? kh : qh) + ((size_t)h*S_TOTC + tok)*HDM + d;
    uint2 ov; ov.x = pk2(o0,o1); ov.y = pk2(o2,o3);
    *(uint2*)dst = ov;
  } else if (blk < 16320){
    int bv = blk - 15360;
    int h = bv % NH, tb = bv / NH;
    int tok0 = tb*64, tid = threadIdx.x;
    #pragma unroll
    for (int i=0;i<4;i++){
      int q = tid + 256*i;
      int tr = q>>4, c8 = (q&15)*8;
      int tok = tok0 + tr;
      const u16* src = ((tok<S_TXTC)? qkvT + (size_t)tok*(3*DM) : qkvI + (size_t)(tok-S_TXTC)*(3*DM))
                       + 2*DM + h*HDM;
      *(s16x8*)&t[tr*136 + c8] = *(const s16x8*)(src + c8);
    }
    __syncthreads();
    #pragma unroll
    for (int i=0;i<4;i++){
      int q = tid + 256*i;
      int d = q>>3, j8 = (q&7)*8;
      s16x8 v;
      #pragma unroll
      for (int j=0;j<8;j++) v[j] = (short)t[(j8+j)*136 + d];
      *(s16x8*)(vt + ((size_t)h*HDM + d)*S_TOTC + tok0 + j8) = v;
    }
  } else {
    // adapter: 96 blocks = 2 tensors x 48 col-strips of 64; lanes sweep W rows (coalesced)
    int bv = blk - 16320;
    int tensor = bv / 48;
    int col = (bv % 48)*64 + (threadIdx.x & 63);
    int tok = threadIdx.x >> 6;
    const float* Wp = tensor? Wvad : Wkad;
    const float* arow = ad + tok*1024;
    float s = 0.f;
    #pragma unroll 4
    for (int k=0;k<1024;k++)
      s += arow[k] * Wp[(size_t)k*DM + col];
    int hh = col>>7, d = col&127;
    (tensor? vdv : vdk)[(hh*4+tok)*HDM + d] = f2b(s);
  }
}

// ---------------- attn: QBLK=128, 8 waves, KVBLK=64, g2l16 dbuf, native-exp2, setprio, XCD-chunked ----------------
__global__ __launch_bounds__(512,2) void attnk(const u16* __restrict__ qh, const u16* __restrict__ kh,
    const u16* __restrict__ vt, const u16* __restrict__ vdk, const u16* __restrict__ vdv,
    const float* __restrict__ bscale, u16* __restrict__ hs){
  __shared__ __align__(16) u16 kts[2][64*128];   // [key][d], slot ^= row&7 (via pre-swizzled source)
  __shared__ __align__(16) u16 vts[2][128*64];   // [d][key], slot ^= row&7
  __shared__ __align__(16) u16 pwb[128*64];      // [q][key], slot ^= row&7 (wave-private rows)
  // XCD-chunked swizzle over 480 blocks: each XCD gets 60 consecutive (qb,h) pairs (= 3 whole heads)
  int id = blockIdx.y*20 + blockIdx.x;
  int nid = (id&7)*60 + (id>>3);
  int qb = (nid % 20)*128, h = nid / 20;
  int tid = threadIdx.x, w = tid>>6, l = tid&63, g = l>>4, c16 = l&15;
  int qrow = qb + w*16 + c16;
  int c7 = c16&7;
  s16x8 qf[4];
  #pragma unroll
  for (int kc=0;kc<4;kc++) qf[kc] = *(const s16x8*)(qh + ((size_t)h*S_TOTC + qrow)*HDM + kc*32 + g*8);
  f32x4 acc[8];
  #pragma unroll
  for (int dt=0;dt<8;dt++) acc[dt] = f32x4{0.f,0.f,0.f,0.f};
  float m_[4] = {-3e38f,-3e38f,-3e38f,-3e38f};
  float l_[4] = {0.f,0.f,0.f,0.f};
  const u16* khB = kh + (size_t)h*S_TOTC*HDM;
  const u16* vtB = vt + (size_t)h*HDM*S_TOTC;

  auto STAGE = [&](int buf, int kb){
    #pragma unroll
    for (int c=0;c<2;c++){
      int krow = w*8 + c*4 + (l>>4);
      int kchunk = (l&15) ^ (krow&7);
      g2l16(khB + (size_t)(kb + krow)*HDM + kchunk*8, &kts[buf][w*1024 + c*512]);
      int vrow = w*16 + c*8 + (l>>3);
      int vchunk = (l&7) ^ (vrow&7);
      g2l16(vtB + (size_t)vrow*S_TOTC + kb + vchunk*8, &vts[buf][w*1024 + c*512]);
    }
  };
  auto COMPUTE = [&](int buf){
    f32x4 s[4];
    #pragma unroll
    for (int su=0;su<4;su++) s[su] = f32x4{0.f,0.f,0.f,0.f};
    __builtin_amdgcn_s_setprio(1);
    #pragma unroll
    for (int su=0;su<4;su++)
      #pragma unroll
      for (int kc=0;kc<4;kc++){
        s16x8 kf = *(const s16x8*)&kts[buf][(su*16+c16)*128 + ((kc*4+g) ^ c7)*8];
        s[su] = __builtin_amdgcn_mfma_f32_16x16x32_bf16(qf[kc], kf, s[su], 0,0,0);
      }
    __builtin_amdgcn_s_setprio(0);
    float tm[4];
    #pragma unroll
    for (int r=0;r<4;r++)
      tm[r] = fmaxf(fmaxf(s[0][r],s[1][r]), fmaxf(s[2][r],s[3][r]));
    #pragma unroll
    for (int m=1;m<16;m<<=1)
      #pragma unroll
      for (int r=0;r<4;r++) tm[r] = fmaxf(tm[r], __shfl_xor(tm[r], m));
    bool need = !__all(tm[0]<=m_[0]+11.5415603f && tm[1]<=m_[1]+11.5415603f &&
                       tm[2]<=m_[2]+11.5415603f && tm[3]<=m_[3]+11.5415603f);
    if (need){
      float corr[4];
      #pragma unroll
      for (int r=0;r<4;r++){
        float mn = fmaxf(m_[r], tm[r]);
        corr[r] = fexp2(m_[r]-mn);
        m_[r] = mn;
        l_[r] *= corr[r];
      }
      #pragma unroll
      for (int dt=0;dt<8;dt++)
        #pragma unroll
        for (int r=0;r<4;r++) acc[dt][r] *= corr[r];
    }
    float rs[4];
    #pragma unroll
    for (int r=0;r<4;r++){
      rs[r] = 0.f;
      #pragma unroll
      for (int su=0;su<4;su++){ s[su][r] = fexp2(s[su][r]-m_[r]); rs[r] += s[su][r]; }
    }
    #pragma unroll
    for (int m=1;m<16;m<<=1)
      #pragma unroll
      for (int r=0;r<4;r++) rs[r] += __shfl_xor(rs[r], m);
    #pragma unroll
    for (int r=0;r<4;r++) l_[r] += rs[r];
    #pragma unroll
    for (int su=0;su<4;su++){
      int kslot = su*2 + (c16>>3);
      #pragma unroll
      for (int r=0;r<4;r++){
        int prow = w*16 + g*4 + r;
        pwb[prow*64 + (kslot ^ (prow&7))*8 + c7] = f2b(s[su][r]);
      }
    }
    int prow = w*16 + c16;
    s16x8 pf0 = *(const s16x8*)&pwb[prow*64 + ((0+g) ^ c7)*8];
    s16x8 pf1 = *(const s16x8*)&pwb[prow*64 + ((4+g) ^ c7)*8];
    __builtin_amdgcn_s_setprio(1);
    #pragma unroll
    for (int dt=0;dt<8;dt++){
      int vrow = dt*16 + c16;
      s16x8 vf0 = *(const s16x8*)&vts[buf][vrow*64 + ((0+g) ^ c7)*8];
      acc[dt] = __builtin_amdgcn_mfma_f32_16x16x32_bf16(pf0, vf0, acc[dt], 0,0,0);
      s16x8 vf1 = *(const s16x8*)&vts[buf][vrow*64 + ((4+g) ^ c7)*8];
      acc[dt] = __builtin_amdgcn_mfma_f32_16x16x32_bf16(pf1, vf1, acc[dt], 0,0,0);
    }
    __builtin_amdgcn_s_setprio(0);
  };

  STAGE(0, 0);
  __syncthreads();
  int cur = 0;
  for (int kb=0; kb<S_TOTC; kb+=64){
    if (kb+64 < S_TOTC) STAGE(cur^1, kb+64);
    COMPUTE(cur);
    __syncthreads();
    cur ^= 1;
  }

  // adapter cross-attention tile (4 valid keys), native exp2, stale rows masked by P=0
  if (tid < 64){
    int row = tid>>4, slot = (tid&15) ^ (row&7);
    *(s16x8*)&kts[0][row*128 + slot*8] = *(const s16x8*)(vdk + (h*4+(tid>>4))*HDM + (tid&15)*8);
  } else if (tid < 192){
    int d = tid - 64;
    int sl0 = (d&7)*8;
    #pragma unroll
    for (int key=0;key<4;key++) vts[0][d*64 + sl0 + key] = vdv[(h*4+key)*HDM + d];
  }
  __syncthreads();
  f32x4 s2 = {0.f,0.f,0.f,0.f};
  #pragma unroll
  for (int kc=0;kc<4;kc++){
    s16x8 kf = *(const s16x8*)&kts[0][c16*128 + ((kc*4+g) ^ c7)*8];
    s2 = __builtin_amdgcn_mfma_f32_16x16x32_bf16(qf[kc], kf, s2, 0,0,0);
  }
  bool valid = (c16 < 4);
  float m2[4], l2[4];
  #pragma unroll
  for (int r=0;r<4;r++) m2[r] = valid? s2[r] : -3e38f;
  #pragma unroll
  for (int m=1;m<16;m<<=1)
    #pragma unroll
    for (int r=0;r<4;r++) m2[r] = fmaxf(m2[r], __shfl_xor(m2[r], m));
  #pragma unroll
  for (int r=0;r<4;r++){ float p = valid? fexp2(s2[r]-m2[r]) : 0.f; s2[r]=p; l2[r]=p; }
  #pragma unroll
  for (int m=1;m<16;m<<=1)
    #pragma unroll
    for (int r=0;r<4;r++) l2[r] += __shfl_xor(l2[r], m);
  #pragma unroll
  for (int r=0;r<4;r++){
    int prow = w*16 + g*4 + r;
    int s0 = (c16>>3) ^ (prow&7);
    int s1 = (2 + (c16>>3)) ^ (prow&7);
    pwb[prow*64 + s0*8 + c7] = f2b(s2[r]);
    pwb[prow*64 + s1*8 + c7] = (u16)0;
  }
  int prow2 = w*16 + c16;
  s16x8 pf2 = *(const s16x8*)&pwb[prow2*64 + (g ^ c7)*8];
  f32x4 a2[8];
  #pragma unroll
  for (int dt=0;dt<8;dt++) a2[dt] = f32x4{0.f,0.f,0.f,0.f};
  #pragma unroll
  for (int dt=0;dt<8;dt++){
    int vrow = dt*16 + c16;
    s16x8 vf = *(const s16x8*)&vts[0][vrow*64 + (g ^ c7)*8];
    a2[dt] = __builtin_amdgcn_mfma_f32_16x16x32_bf16(pf2, vf, a2[dt], 0,0,0);
  }
  float sb = bscale[0];
  float rl[4], rl2[4];
  #pragma unroll
  for (int r=0;r<4;r++){ rl[r] = 1.f/l_[r]; rl2[r] = sb/l2[r]; }
  #pragma unroll
  for (int dt=0;dt<8;dt++)
    #pragma unroll
    for (int r=0;r<4;r++){
      int tok = qb + w*16 + g*4 + r;
      int col = h*HDM + dt*16 + c16;
      hs[(size_t)tok*DM + col] = f2b(acc[dt][r]*rl[r] + a2[dt][r]*rl2[r]);
    }
}

extern "C" void kernel_launch(void* const* d_in, const int* in_sizes, int n_in,
                              void* d_out, int out_size, void* d_ws, size_t ws_size,
                              hipStream_t stream){
  static const int expect[28] = {
    6291456, 1572864, 4096, 327680, 327680,
    9437184, 3072, 9437184, 3072, 9437184, 3072, 128, 128,
    9437184, 3072, 9437184, 3072, 9437184, 3072, 128, 128,
    9437184, 3072, 9437184, 3072, 3145728, 3145728, 1 };
  bool ok = (n_in == 28);
  if (ok) for (int i=0;i<28;i++) if (in_sizes[i] != expect[i]) { ok = false; break; }
  if (!ok){ fillv<<<(out_size+255)/256,256,0,stream>>>((float*)d_out, out_size, 7.0f); return; }
  if (ws_size < 119611392ull){ fillv<<<(out_size+255)/256,256,0,stream>>>((float*)d_out, out_size, 9.0f); return; }

  const float* hidden = (const float*)d_in[0];
  const float* enc    = (const float*)d_in[1];
  const float* adapt  = (const float*)d_in[2];
  const float* fcos   = (const float*)d_in[3];
  const float* fsin   = (const float*)d_in[4];
  const float* Wq  = (const float*)d_in[5];  const float* bq  = (const float*)d_in[6];
  const float* Wk  = (const float*)d_in[7];  const float* bk  = (const float*)d_in[8];
  const float* Wv  = (const float*)d_in[9];  const float* bv  = (const float*)d_in[10];
  const float* nqw = (const float*)d_in[11]; const float* nkw = (const float*)d_in[12];
  const float* Wqa = (const float*)d_in[13]; const float* bqa = (const float*)d_in[14];
  const float* Wka = (const float*)d_in[15]; const float* bka = (const float*)d_in[16];
  const float* Wva = (const float*)d_in[17]; const float* bva = (const float*)d_in[18];
  const float* naq = (const float*)d_in[19]; const float* nak = (const float*)d_in[20];
  const float* Wo  = (const float*)d_in[21]; const float* bo  = (const float*)d_in[22];
  const float* Woa = (const float*)d_in[23]; const float* boa = (const float*)d_in[24];
  const float* Wkad = (const float*)d_in[25]; const float* Wvad = (const float*)d_in[26];
  const float* bsc  = (const float*)d_in[27];
  float* out = (float*)d_out;

  char* ws = (char*)d_ws;
  u16* wt3   = (u16*)(ws);
  u16* kh    = (u16*)(ws);
  u16* vth   = (u16*)(ws + 15728640);
  u16* vdk   = (u16*)(ws + 31457280);
  u16* vdv   = (u16*)(ws + 31481856);
  u16* woaT  = (u16*)(ws + 33554432);
  u16* hbf   = (u16*)(ws + 56623104);
  u16* qh    = (u16*)(ws + 56623104);
  u16* qkvI  = (u16*)(ws + 72351744);
  u16* hsb   = (u16*)(ws + 72351744);
  u16* woT   = (u16*)(ws + 88080384);
  u16* qkvT  = (u16*)(ws + 110100480);
  float* biasA = (float*)(ws + 119537664);
  float* biasB = (float*)(ws + 119574528);

  castbias<<<3912,256,0,stream>>>(hidden, enc, hbf, 786432, 983040,
                                  bq,bk,bv, bqa,bka,bva, biasA);
  // img QKV: transpose Wq/Wk/Wv then GEMM
  ktrans3<<<dim3(48,48,3),256,0,stream>>>(Wq, Wk, Wv, wt3, wt3 + (size_t)DM*DM, wt3 + (size_t)2*DM*DM);
  qkv_gemm<<<dim3(16,72),256,0,stream>>>(hbf, wt3, biasA, qkvI);
  // txt QKV: transpose Wqa/Wka/Wva (REQUIRED - reuses wt3) then GEMM
  ktrans3<<<dim3(48,48,3),256,0,stream>>>(Wqa, Wka, Wva, wt3, wt3 + (size_t)DM*DM, wt3 + (size_t)2*DM*DM);
  qkv_gemm<<<dim3(4,72),256,0,stream>>>(hbf + (size_t)2048*DM, wt3, biasB, qkvT);
  epi_fused<<<16416,256,0,stream>>>(qkvI, qkvT, nqw,nkw,naq,nak, fcos,fsin, qh, kh, vth,
                                    adapt, Wkad, Wvad, vdk, vdv);
  attnk<<<dim3(20,24),512,0,stream>>>(qh, kh, vth, vdk, vdv, bsc, hsb);
  ktrans3<<<dim3(48,48,2),256,0,stream>>>(Wo, Woa, Woa, woT, woaT, woaT);
  out_gemm<<<dim3(20,24),256,0,stream>>>(hsb, woT, woaT, bo, boa, out);
}